// Round 8
// baseline (818.690 us; speedup 1.0000x reference)
//
#include <hip/hip_runtime.h>
#include <hip/hip_bf16.h>
#include <math.h>

// Problem constants
#define B_N 4096
#define BITSN 64
#define HID 512
#define EPSV 1e-5f
#define BT 16   // batch rows per shift2 block

typedef unsigned short ushort_t;
typedef __attribute__((ext_vector_type(8))) short bf16x8;
typedef __attribute__((ext_vector_type(4))) float f32x4;
typedef __attribute__((ext_vector_type(16))) float f32x16;

__device__ __forceinline__ ushort_t f2bf(float f) {
  unsigned u = __float_as_uint(f);
  u += 0x7FFF + ((u >> 16) & 1);   // round-to-nearest-even
  return (ushort_t)(u >> 16);
}

__device__ __forceinline__ unsigned pack2bf(float lo, float hi) {
  union { __hip_bfloat162 h; unsigned u; } cv;
  cv.h = __float22bfloat162_rn(make_float2(lo, hi));  // v_cvt_pk_bf16_f32
  return cv.u;
}

// ---------------- prep: bf16 copies, transposes, FRAGMENT-ORDER weights ----
// Wi2f32: 32x32x16 frag order (GEMM1 B). Frag (ks 0..31, ct 0..15) lane l:
//   Wi2[ct*32 + (l&31)][ks*16 + (l>>5)*8 + j].
// Wi3g: GEMM2 B in the SAME (e,hi)->c permutation our in-register h2 pack
//   produces: idx=((((w*2+mc)*2+h)*2+jt)*64+l)*8+e ->
//   Wi3[jt*32+(l&31)][w*64+mc*32+16h+4*(l>>5)+(e&3)+8*(e>>2)].
__global__ __launch_bounds__(256) void prep_kernel(
    const float* __restrict__ Wi2, const float* __restrict__ Wi3,
    const float* __restrict__ Wi1, const float* __restrict__ W1,
    const float* __restrict__ W2, const float* __restrict__ W3,
    float* __restrict__ Wi1posT, ushort_t* __restrict__ W1b,
    ushort_t* __restrict__ W2b, ushort_t* __restrict__ W3b,
    ushort_t* __restrict__ Wi1sb, ushort_t* __restrict__ Wi2f32,
    ushort_t* __restrict__ Wi3g) {
  int idx = blockIdx.x * 256 + threadIdx.x;
  if (idx < 512 * 512) {
    W2b[idx] = f2bf(W2[idx]);
    // Wi2f32 frag-order scatter (dst-linear, coalesced writes)
    int j = idx & 7, lane = (idx >> 3) & 63;
    int ct = (idx >> 9) & 15, ks = idx >> 13;
    int c = ct * 32 + (lane & 31);
    int k = ks * 16 + (lane >> 5) * 8 + j;
    Wi2f32[idx] = f2bf(Wi2[c * 512 + k]);
  }
  if (idx < 64 * 512) {
    W3b[idx] = f2bf(W3[idx]);
    int p = idx >> 9, i = idx & 511;
    Wi1posT[idx] = Wi1[i * 128 + p];   // pos_part[p][i] = Wi1[i][p]
    // Wi3g dst-linear scatter
    int e = idx & 7, lane = (idx >> 3) & 63;
    int jt = (idx >> 9) & 1, h = (idx >> 10) & 1;
    int mc = (idx >> 11) & 1, w = idx >> 12;
    int jr = jt * 32 + (lane & 31);
    int c = w * 64 + mc * 32 + 16 * h + 4 * (lane >> 5) + (e & 3) + 8 * (e >> 2);
    Wi3g[idx] = f2bf(Wi3[jr * 512 + c]);
  }
  if (idx < 512 * 64) {
    W1b[idx] = f2bf(W1[idx]);                       // [512][64]
    int j = idx >> 6, k = idx & 63;
    Wi1sb[idx] = f2bf(Wi1[j * 128 + 64 + k]);       // shift cols of Wi1: [512][64]
  }
}

// ---------------- shift decoder, MFMA-batched: 16 rows/block ----------------
__global__ __launch_bounds__(256) void shift2_kernel(
    const float* __restrict__ shift_bits,
    const ushort_t* __restrict__ W1b, const float* __restrict__ b1,
    const float* __restrict__ g1, const float* __restrict__ be1,
    const ushort_t* __restrict__ W2b, const float* __restrict__ b2,
    const float* __restrict__ g2, const float* __restrict__ be2,
    const ushort_t* __restrict__ W3b, const float* __restrict__ b3,
    const ushort_t* __restrict__ Wi1sb, const float* __restrict__ bi1,
    float* __restrict__ sp) {
  __shared__ __align__(16) ushort_t hA[BT * 512];     // 16KB: h1 (post LN1+relu)
  __shared__ __align__(16) char reg2[32 * 1024];      // phase union
  __shared__ float b1s[512], g1s[512], be1s[512];
  __shared__ float b2s[512], g2s[512], be2s[512], bi1s[512];
  __shared__ float red[4][BT][2];
  __shared__ float b3s[64];

  ushort_t* sbt = (ushort_t*)reg2;                    // phase 1: shift_bits tile [16][64]
  ushort_t* Bs  = (ushort_t*)reg2;                    // phase 2: W2 tile [512][32]
  ushort_t* h2  = (ushort_t*)reg2;                    // phase 3: h2 [16][512]
  float (*lg32)[68] = (float(*)[68])(reg2 + 16 * 1024);
  ushort_t* sb2 = (ushort_t*)(reg2 + 16 * 1024 + 16 * 68 * 4);  // soft [16][64]

  int b0 = blockIdx.x * BT;
  int t = threadIdx.x, w = t >> 6, l = t & 63, lg = l >> 4, l15 = l & 15;

  b1s[t] = b1[t];  b1s[t + 256] = b1[t + 256];
  g1s[t] = g1[t];  g1s[t + 256] = g1[t + 256];
  be1s[t] = be1[t]; be1s[t + 256] = be1[t + 256];
  b2s[t] = b2[t];  b2s[t + 256] = b2[t + 256];
  g2s[t] = g2[t];  g2s[t + 256] = g2[t + 256];
  be2s[t] = be2[t]; be2s[t + 256] = be2[t + 256];
  bi1s[t] = bi1[t]; bi1s[t + 256] = bi1[t + 256];
  if (t < 64) b3s[t] = b3[t];
  if (t < 128) {   // stage shift_bits tile -> bf16 swizzled
    int row = t >> 3, g = t & 7;
    const float* src = shift_bits + (size_t)(b0 + row) * 64 + g * 8;
    uint4 pk;
    pk.x = (unsigned)f2bf(src[0]) | ((unsigned)f2bf(src[1]) << 16);
    pk.y = (unsigned)f2bf(src[2]) | ((unsigned)f2bf(src[3]) << 16);
    pk.z = (unsigned)f2bf(src[4]) | ((unsigned)f2bf(src[5]) << 16);
    pk.w = (unsigned)f2bf(src[6]) | ((unsigned)f2bf(src[7]) << 16);
    *(uint4*)((char*)sbt + ((row * 128 + g * 16) ^ ((row & 7) << 4))) = pk;
  }
  __syncthreads();

  // ----- GEMM1: x1[16][512] = sbt @ W1^T ; wave w owns cols [w*128, w*128+128) -----
  f32x4 acc[8];
#pragma unroll
  for (int nt = 0; nt < 8; ++nt) acc[nt] = (f32x4){0.f, 0.f, 0.f, 0.f};
#pragma unroll
  for (int ks = 0; ks < 2; ++ks) {
    bf16x8 af = *(const bf16x8*)((char*)sbt + ((l15 * 128 + ks * 64 + lg * 16) ^ ((l15 & 7) << 4)));
#pragma unroll
    for (int nt = 0; nt < 8; ++nt) {
      int c = w * 128 + nt * 16 + l15;
      bf16x8 bfr = *(const bf16x8*)(W1b + (size_t)c * 64 + ks * 32 + lg * 8);
      acc[nt] = __builtin_amdgcn_mfma_f32_16x16x32_bf16(af, bfr, acc[nt], 0, 0, 0);
    }
  }
  // ----- LN1 + relu -> hA -----
  {
    float s[4] = {0.f, 0.f, 0.f, 0.f}, q[4] = {0.f, 0.f, 0.f, 0.f};
#pragma unroll
    for (int nt = 0; nt < 8; ++nt) {
      int c = w * 128 + nt * 16 + l15;
      float bb = b1s[c];
#pragma unroll
      for (int r = 0; r < 4; ++r) {
        float x = acc[nt][r] + bb;
        acc[nt][r] = x;
        s[r] += x; q[r] += x * x;
      }
    }
#pragma unroll
    for (int m = 8; m >= 1; m >>= 1)
#pragma unroll
      for (int r = 0; r < 4; ++r) { s[r] += __shfl_xor(s[r], m); q[r] += __shfl_xor(q[r], m); }
    if (l15 == 0)
#pragma unroll
      for (int r = 0; r < 4; ++r) { red[w][4 * lg + r][0] = s[r]; red[w][4 * lg + r][1] = q[r]; }
    __syncthreads();
    float mean[4], rs[4];
#pragma unroll
    for (int r = 0; r < 4; ++r) {
      int p = 4 * lg + r;
      float S = red[0][p][0] + red[1][p][0] + red[2][p][0] + red[3][p][0];
      float Q = red[0][p][1] + red[1][p][1] + red[2][p][1] + red[3][p][1];
      mean[r] = S * (1.0f / 512.0f);
      float var = Q * (1.0f / 512.0f) - mean[r] * mean[r];
      rs[r] = rsqrtf(var + EPSV);
    }
#pragma unroll
    for (int nt = 0; nt < 8; ++nt) {
      int c = w * 128 + nt * 16 + l15;
      float gg = g1s[c], bb = be1s[c];
#pragma unroll
      for (int r = 0; r < 4; ++r) {
        int p = 4 * lg + r;
        float v = (acc[nt][r] - mean[r]) * rs[r] * gg + bb;
        v = v > 0.f ? v : 0.f;
        *(ushort_t*)((char*)hA + ((p * 1024 + c * 2) ^ ((p & 7) << 4))) = f2bf(v);
      }
    }
  }
  __syncthreads();

  // ----- GEMM2: x2[16][512] = hA @ W2^T, K=512 staged in 16 chunks of 32 -----
#pragma unroll
  for (int nt = 0; nt < 8; ++nt) acc[nt] = (f32x4){0.f, 0.f, 0.f, 0.f};
  for (int step = 0; step < 16; ++step) {
    int i0 = step * 32;
#pragma unroll
    for (int qq = 0; qq < 8; ++qq) {   // stage Bs [512][32] swizzled (linear writes)
      int g = qq * 256 + t;
      int c = g >> 2, xg = g & 3;
      int ic = xg ^ ((c >> 1) & 3);
      ((uint4*)Bs)[g] = *(const uint4*)(W2b + (size_t)c * 512 + i0 + ic * 8);
    }
    __syncthreads();
    bf16x8 af = *(const bf16x8*)((char*)hA + ((l15 * 1024 + step * 64 + lg * 16) ^ ((l15 & 7) << 4)));
#pragma unroll
    for (int nt = 0; nt < 8; ++nt) {
      int c = w * 128 + nt * 16 + l15;
      bf16x8 bfr = ((const bf16x8*)Bs)[c * 4 + (lg ^ ((c >> 1) & 3))];
      acc[nt] = __builtin_amdgcn_mfma_f32_16x16x32_bf16(af, bfr, acc[nt], 0, 0, 0);
    }
    __syncthreads();
  }
  // ----- LN2 + relu -> h2 (overwrites Bs region; safe: barrier above) -----
  {
    float s[4] = {0.f, 0.f, 0.f, 0.f}, q[4] = {0.f, 0.f, 0.f, 0.f};
#pragma unroll
    for (int nt = 0; nt < 8; ++nt) {
      int c = w * 128 + nt * 16 + l15;
      float bb = b2s[c];
#pragma unroll
      for (int r = 0; r < 4; ++r) {
        float x = acc[nt][r] + bb;
        acc[nt][r] = x;
        s[r] += x; q[r] += x * x;
      }
    }
#pragma unroll
    for (int m = 8; m >= 1; m >>= 1)
#pragma unroll
      for (int r = 0; r < 4; ++r) { s[r] += __shfl_xor(s[r], m); q[r] += __shfl_xor(q[r], m); }
    if (l15 == 0)
#pragma unroll
      for (int r = 0; r < 4; ++r) { red[w][4 * lg + r][0] = s[r]; red[w][4 * lg + r][1] = q[r]; }
    __syncthreads();
    float mean[4], rs[4];
#pragma unroll
    for (int r = 0; r < 4; ++r) {
      int p = 4 * lg + r;
      float S = red[0][p][0] + red[1][p][0] + red[2][p][0] + red[3][p][0];
      float Q = red[0][p][1] + red[1][p][1] + red[2][p][1] + red[3][p][1];
      mean[r] = S * (1.0f / 512.0f);
      float var = Q * (1.0f / 512.0f) - mean[r] * mean[r];
      rs[r] = rsqrtf(var + EPSV);
    }
#pragma unroll
    for (int nt = 0; nt < 8; ++nt) {
      int c = w * 128 + nt * 16 + l15;
      float gg = g2s[c], bb = be2s[c];
#pragma unroll
      for (int r = 0; r < 4; ++r) {
        int p = 4 * lg + r;
        float v = (acc[nt][r] - mean[r]) * rs[r] * gg + bb;
        v = v > 0.f ? v : 0.f;
        *(ushort_t*)((char*)h2 + ((p * 1024 + c * 2) ^ ((p & 7) << 4))) = f2bf(v);
      }
    }
  }
  __syncthreads();

  // ----- GEMM3: logits[16][64] = h2 @ W3^T ; wave w owns cols [16w,16w+16) -----
  {
    f32x4 a3 = (f32x4){0.f, 0.f, 0.f, 0.f};
#pragma unroll
    for (int ks = 0; ks < 16; ++ks) {
      bf16x8 af = *(const bf16x8*)((char*)h2 + ((l15 * 1024 + ks * 64 + lg * 16) ^ ((l15 & 7) << 4)));
      bf16x8 bfr = *(const bf16x8*)(W3b + (size_t)(w * 16 + l15) * 512 + ks * 32 + lg * 8);
      a3 = __builtin_amdgcn_mfma_f32_16x16x32_bf16(af, bfr, a3, 0, 0, 0);
    }
    int c = w * 16 + l15;
    float bb = b3s[c];
#pragma unroll
    for (int r = 0; r < 4; ++r) lg32[4 * lg + r][c] = a3[r] + bb;
  }
  __syncthreads();

  // ----- softmax over 64 logits -> sb2 (bf16, swizzled) -----
  {
    int r = t >> 4, j = t & 15;
    float v[4];
    float m = -1e30f;
#pragma unroll
    for (int mq = 0; mq < 4; ++mq) { v[mq] = lg32[r][mq * 16 + j]; m = fmaxf(m, v[mq]); }
#pragma unroll
    for (int mk = 8; mk >= 1; mk >>= 1) m = fmaxf(m, __shfl_xor(m, mk));
    float ssum = 0.f;
#pragma unroll
    for (int mq = 0; mq < 4; ++mq) { v[mq] = expf(v[mq] - m); ssum += v[mq]; }
#pragma unroll
    for (int mk = 8; mk >= 1; mk >>= 1) ssum += __shfl_xor(ssum, mk);
    float inv = 1.f / ssum;
#pragma unroll
    for (int mq = 0; mq < 4; ++mq) {
      int c = mq * 16 + j;
      *(ushort_t*)((char*)sb2 + ((r * 128 + c * 2) ^ ((r & 7) << 4))) = f2bf(v[mq] * inv);
    }
  }
  __syncthreads();

  // ----- GEMM4: sp[16][512] = soft @ Wi1shift^T + bi1 -----
  {
    f32x4 a4[8];
#pragma unroll
    for (int nt = 0; nt < 8; ++nt) a4[nt] = (f32x4){0.f, 0.f, 0.f, 0.f};
#pragma unroll
    for (int ks = 0; ks < 2; ++ks) {
      bf16x8 af = *(const bf16x8*)((char*)sb2 + ((l15 * 128 + ks * 64 + lg * 16) ^ ((l15 & 7) << 4)));
#pragma unroll
      for (int nt = 0; nt < 8; ++nt) {
        int c = w * 128 + nt * 16 + l15;
        bf16x8 bfr = *(const bf16x8*)(Wi1sb + (size_t)c * 64 + ks * 32 + lg * 8);
        a4[nt] = __builtin_amdgcn_mfma_f32_16x16x32_bf16(af, bfr, a4[nt], 0, 0, 0);
      }
    }
#pragma unroll
    for (int nt = 0; nt < 8; ++nt) {
      int c = w * 128 + nt * 16 + l15;
      float bb = bi1s[c];
#pragma unroll
      for (int r = 0; r < 4; ++r)
        sp[(size_t)(b0 + 4 * lg + r) * 512 + c] = a4[nt][r] + bb;
    }
  }
}

// ---------------- big7: in-register GEMM1->GEMM2 fusion ----------------
// BM=64 (1 batch row), BN=512, 8 waves. h1[64][512] LDS panel (&15 swizzle).
// GEMM1 = mfma(Wi2frag, h1frag): lane<->p, reg<->c. h2 stays IN REGISTERS:
// relu+bias, cvt_pk to bf16 A-frags, then GEMM2 = mfma(h2frag, Wi3gfrag)
// per-wave over its 64-c chunk (k-permutation baked into Wi3g by prep).
// Cross-wave K-reduction: atomicAdd into logits[64][64] f32 (aliases h1s,
// bias-pre-initialized). Max-free softmax (logits ~ +-1) on all 512 threads.
__global__ __launch_bounds__(512, 4) void big7_kernel(
    const float* __restrict__ a_bits, const float* __restrict__ sp,
    const float* __restrict__ Wi1posT,
    const ushort_t* __restrict__ Wi2f32, const ushort_t* __restrict__ Wi3g,
    const float* __restrict__ bi2, const float* __restrict__ bi3,
    float* __restrict__ out) {
  __shared__ __align__(16) ushort_t h1s[64 * 512];   // 64KB; reused as logits[64][64] f32
  __shared__ float bi2s[512];
  __shared__ float ab[64];
  __shared__ float bi3s[64];

  int b = blockIdx.x, t = threadIdx.x;
  int w = t >> 6, l = t & 63;
  int l31 = l & 31, hi = l >> 5;

  bi2s[t] = bi2[t];
  if (t < 64) { ab[t] = a_bits[b * 64 + t]; bi3s[t] = bi3[t]; }

  // ---- phase 0: h1[64][512] = relu(sp[b] + pos) -> LDS bf16, swizzled, ONCE ----
  {
    const float* sprow = sp + (size_t)b * 512 + l * 8;
    float4 s0 = *(const float4*)(sprow);
    float4 s1 = *(const float4*)(sprow + 4);
#pragma unroll
    for (int g = 0; g < 8; ++g) {
      int p = g * 8 + w;                    // wave w covers rows {w, 8+w, ..., 56+w}
      const float4* pr = (const float4*)(Wi1posT + (size_t)p * 512 + l * 8);
      float4 p0 = pr[0], p1 = pr[1];
      float v0 = fmaxf(s0.x + p0.x, 0.f), v1 = fmaxf(s0.y + p0.y, 0.f);
      float v2 = fmaxf(s0.z + p0.z, 0.f), v3 = fmaxf(s0.w + p0.w, 0.f);
      float v4 = fmaxf(s1.x + p1.x, 0.f), v5 = fmaxf(s1.y + p1.y, 0.f);
      float v6 = fmaxf(s1.z + p1.z, 0.f), v7 = fmaxf(s1.w + p1.w, 0.f);
      uint4 pk;
      pk.x = pack2bf(v0, v1); pk.y = pack2bf(v2, v3);
      pk.z = pack2bf(v4, v5); pk.w = pack2bf(v6, v7);
      *(uint4*)((char*)h1s + ((p * 1024 + l * 16) ^ ((p & 15) << 4))) = pk;
    }
  }
  __syncthreads();

  // ---- GEMM1: mfma(Wi2, h1) ; 32x32x16, depth-4 B prefetch, barrier-free ----
  f32x16 acc[2][2];   // acc[mc][np]: reg<->c (c-tile mc), lane<->p (p-tile np)
#pragma unroll
  for (int mc = 0; mc < 2; ++mc)
#pragma unroll
    for (int np = 0; np < 2; ++np)
#pragma unroll
      for (int r = 0; r < 16; ++r) acc[mc][np][r] = 0.f;

  {
    const bf16x8* bbase = (const bf16x8*)Wi2f32 + ((size_t)(2 * w) * 64 + l);
    bf16x8 wf[4][2];
#pragma unroll
    for (int d = 0; d < 4; ++d) {
      wf[d][0] = bbase[(size_t)d * 1024];
      wf[d][1] = bbase[(size_t)d * 1024 + 64];
    }
    for (int kb = 0; kb < 8; ++kb) {
#pragma unroll
      for (int d = 0; d < 4; ++d) {
        int ks = kb * 4 + d;
        bf16x8 w0 = wf[d][0], w1 = wf[d][1];
        if (kb < 7) {
          wf[d][0] = bbase[(size_t)(ks + 4) * 1024];
          wf[d][1] = bbase[(size_t)(ks + 4) * 1024 + 64];
        }
        int row0 = l31, row1 = 32 + l31;
        bf16x8 h0 = *(const bf16x8*)((char*)h1s + ((row0 * 1024 + ks * 32 + hi * 16) ^ ((row0 & 15) << 4)));
        bf16x8 h1v = *(const bf16x8*)((char*)h1s + ((row1 * 1024 + ks * 32 + hi * 16) ^ ((row1 & 15) << 4)));
        __builtin_amdgcn_s_setprio(1);
        acc[0][0] = __builtin_amdgcn_mfma_f32_32x32x16_bf16(w0, h0, acc[0][0], 0, 0, 0);
        acc[0][1] = __builtin_amdgcn_mfma_f32_32x32x16_bf16(w0, h1v, acc[0][1], 0, 0, 0);
        acc[1][0] = __builtin_amdgcn_mfma_f32_32x32x16_bf16(w1, h0, acc[1][0], 0, 0, 0);
        acc[1][1] = __builtin_amdgcn_mfma_f32_32x32x16_bf16(w1, h1v, acc[1][1], 0, 0, 0);
        __builtin_amdgcn_s_setprio(0);
      }
    }
  }

  // ---- h2 = relu(acc + bi2), pack to bf16 A-frags in regs (frees acc) ----
  // acc[mc][np] reg r: c = w*64 + mc*32 + (r&3)+8*(r>>2)+4*hi ; p = np*32+l31.
  // pack pk[np][mc][h] elem e  <->  c = w*64+mc*32+16h+4hi+(e&3)+8*(e>>2)
  // (e = r-8h; c-pairs consecutive per dword, matches Wi3g prep order).
  bf16x8 pkf[2][2][2];   // [np][mc][h]
#pragma unroll
  for (int mc = 0; mc < 2; ++mc) {
    float bia[16];
#pragma unroll
    for (int rq = 0; rq < 4; ++rq) {
      int c0 = w * 64 + mc * 32 + 8 * rq + 4 * hi;
      float4 bi4 = *(const float4*)(bi2s + c0);
      bia[4 * rq + 0] = bi4.x; bia[4 * rq + 1] = bi4.y;
      bia[4 * rq + 2] = bi4.z; bia[4 * rq + 3] = bi4.w;
    }
#pragma unroll
    for (int np = 0; np < 2; ++np) {
      float hv[16];
#pragma unroll
      for (int r = 0; r < 16; ++r) hv[r] = fmaxf(acc[mc][np][r] + bia[r], 0.f);
#pragma unroll
      for (int h = 0; h < 2; ++h) {
        unsigned d0 = pack2bf(hv[8 * h + 0], hv[8 * h + 1]);
        unsigned d1 = pack2bf(hv[8 * h + 2], hv[8 * h + 3]);
        unsigned d2 = pack2bf(hv[8 * h + 4], hv[8 * h + 5]);
        unsigned d3 = pack2bf(hv[8 * h + 6], hv[8 * h + 7]);
        union { unsigned u[4]; bf16x8 v; } cv;
        cv.u[0] = d0; cv.u[1] = d1; cv.u[2] = d2; cv.u[3] = d3;
        pkf[np][mc][h] = cv.v;
      }
    }
  }
  __syncthreads();   // all waves done reading h1s -> safe to reuse as logits

  // ---- bias-init logits[64][64] f32 (aliases h1s) ----
  float* Lg = (float*)h1s;
  {
    int p = t >> 3, jo = t & 7;
    float4 bA = *(const float4*)(bi3s + jo * 8);
    float4 bB = *(const float4*)(bi3s + jo * 8 + 4);
    *(float4*)(Lg + p * 64 + jo * 8) = bA;
    *(float4*)(Lg + p * 64 + jo * 8 + 4) = bB;
  }
  __syncthreads();

  // ---- GEMM2: partial logits over this wave's 64-c chunk, then ds_add ----
  {
    const bf16x8* gbase = (const bf16x8*)Wi3g + ((size_t)w * 8 * 64 + l);
    f32x16 l00, l01, l10, l11;
#pragma unroll
    for (int r = 0; r < 16; ++r) { l00[r] = 0.f; l01[r] = 0.f; l10[r] = 0.f; l11[r] = 0.f; }
#pragma unroll
    for (int mc = 0; mc < 2; ++mc) {
#pragma unroll
      for (int h = 0; h < 2; ++h) {
        bf16x8 g0 = gbase[((mc * 2 + h) * 2 + 0) * 64];
        bf16x8 g1 = gbase[((mc * 2 + h) * 2 + 1) * 64];
        __builtin_amdgcn_s_setprio(1);
        l00 = __builtin_amdgcn_mfma_f32_32x32x16_bf16(pkf[0][mc][h], g0, l00, 0, 0, 0);
        l01 = __builtin_amdgcn_mfma_f32_32x32x16_bf16(pkf[0][mc][h], g1, l01, 0, 0, 0);
        l10 = __builtin_amdgcn_mfma_f32_32x32x16_bf16(pkf[1][mc][h], g0, l10, 0, 0, 0);
        l11 = __builtin_amdgcn_mfma_f32_32x32x16_bf16(pkf[1][mc][h], g1, l11, 0, 0, 0);
        __builtin_amdgcn_s_setprio(0);
      }
    }
    // D: lane<->j (jt*32+l31), reg<->p (np*32 + (r&3)+8*(r>>2)+4*hi)
#pragma unroll
    for (int r = 0; r < 16; ++r) {
      int prow = (r & 3) + 8 * (r >> 2) + 4 * hi;
      atomicAdd(Lg + (prow)      * 64 + l31,      l00[r]);
      atomicAdd(Lg + (prow)      * 64 + 32 + l31, l01[r]);
      atomicAdd(Lg + (prow + 32) * 64 + l31,      l10[r]);
      atomicAdd(Lg + (prow + 32) * 64 + 32 + l31, l11[r]);
    }
  }
  __syncthreads();

  // ---- max-free softmax + gather (logits tiny: ~N(0,0.2); exp safe) ----
  {
    int p = t >> 3, jo = t & 7;
    float4 vA = *(const float4*)(Lg + p * 64 + jo * 8);
    float4 vB = *(const float4*)(Lg + p * 64 + jo * 8 + 4);
    const float* abp = ab + jo * 8;
    float e0 = __expf(vA.x), e1 = __expf(vA.y), e2 = __expf(vA.z), e3 = __expf(vA.w);
    float e4 = __expf(vB.x), e5 = __expf(vB.y), e6 = __expf(vB.z), e7 = __expf(vB.w);
    float s = e0 + e1 + e2 + e3 + e4 + e5 + e6 + e7;
    float g = e0 * abp[0] + e1 * abp[1] + e2 * abp[2] + e3 * abp[3]
            + e4 * abp[4] + e5 * abp[5] + e6 * abp[6] + e7 * abp[7];
#pragma unroll
    for (int mm = 4; mm >= 1; mm >>= 1) { s += __shfl_xor(s, mm); g += __shfl_xor(g, mm); }
    if (jo == 0) out[b * 64 + p] = g / s;
  }
}

extern "C" void kernel_launch(void* const* d_in, const int* in_sizes, int n_in,
                              void* d_out, int out_size, void* d_ws, size_t ws_size,
                              hipStream_t stream) {
  const float* a_bits     = (const float*)d_in[0];
  const float* shift_bits = (const float*)d_in[1];
  const float* W1  = (const float*)d_in[2];
  const float* b1  = (const float*)d_in[3];
  const float* g1  = (const float*)d_in[4];
  const float* be1 = (const float*)d_in[5];
  const float* W2  = (const float*)d_in[6];
  const float* b2  = (const float*)d_in[7];
  const float* g2  = (const float*)d_in[8];
  const float* be2 = (const float*)d_in[9];
  const float* W3  = (const float*)d_in[10];
  const float* b3  = (const float*)d_in[11];
  const float* Wi1 = (const float*)d_in[12];
  const float* bi1 = (const float*)d_in[13];
  const float* Wi2 = (const float*)d_in[14];
  const float* bi2 = (const float*)d_in[15];
  const float* Wi3 = (const float*)d_in[16];
  const float* bi3 = (const float*)d_in[17];
  float* out = (float*)d_out;

  // ws layout: sp fp32 [B][512] (8MB) | W2b (512KB) | W1b (64KB) | W3b (64KB)
  //            | Wi1sb (64KB) | Wi1posT fp32 (128KB) | Wi2f32 (512KB) | Wi3g (64KB)
  float* sp = (float*)d_ws;
  ushort_t* W2b = (ushort_t*)((char*)d_ws + (size_t)B_N * HID * 4);
  ushort_t* W1b = W2b + 512 * 512;
  ushort_t* W3b = W1b + 512 * 64;
  ushort_t* Wi1sb = W3b + 64 * 512;
  float* Wi1posT = (float*)(Wi1sb + 512 * 64);
  ushort_t* Wi2f32 = (ushort_t*)(Wi1posT + 64 * 512);
  ushort_t* Wi3g = Wi2f32 + 512 * 512;

  prep_kernel<<<1024, 256, 0, stream>>>(Wi2, Wi3, Wi1, W1, W2, W3,
                                        Wi1posT, W1b, W2b, W3b, Wi1sb, Wi2f32, Wi3g);
  shift2_kernel<<<B_N / BT, 256, 0, stream>>>(shift_bits, W1b, b1, g1, be1,
                                              W2b, b2, g2, be2, W3b, b3, Wi1sb, bi1, sp);
  big7_kernel<<<B_N, 512, 0, stream>>>(a_bits, sp, Wi1posT, Wi2f32, Wi3g, bi2, bi3, out);
}

// Round 9
// 204.345 us; speedup vs baseline: 4.0064x; 4.0064x over previous
//
#include <hip/hip_runtime.h>
#include <hip/hip_bf16.h>
#include <math.h>

// Problem constants
#define B_N 4096
#define BITSN 64
#define HID 512
#define EPSV 1e-5f
#define BT 16   // batch rows per shift2 block

typedef unsigned short ushort_t;
typedef __attribute__((ext_vector_type(8))) short bf16x8;
typedef __attribute__((ext_vector_type(4))) float f32x4;
typedef __attribute__((ext_vector_type(16))) float f32x16;

__device__ __forceinline__ ushort_t f2bf(float f) {
  unsigned u = __float_as_uint(f);
  u += 0x7FFF + ((u >> 16) & 1);   // round-to-nearest-even
  return (ushort_t)(u >> 16);
}

__device__ __forceinline__ unsigned pack2bf(float lo, float hi) {
  union { __hip_bfloat162 h; unsigned u; } cv;
  cv.h = __float22bfloat162_rn(make_float2(lo, hi));  // v_cvt_pk_bf16_f32
  return cv.u;
}

__device__ __forceinline__ float bf2f(short v) {
  return __uint_as_float(((unsigned)(unsigned short)v) << 16);
}

// ---------------- prep: bf16 copies, transposes, FRAGMENT-ORDER weights ----
// Wi2f32: 32x32x16 frag order (GEMM1 B). Frag (ks 0..31, ct 0..15) lane l:
//   Wi2[ct*32 + (l&31)][ks*16 + (l>>5)*8 + j].
// Wi3g: GEMM2 B in the (e,hi)->c permutation the in-register h2 pack produces
//   (verified correct in R8): idx=((((w*2+mc)*2+h)*2+jt)*64+l)*8+e ->
//   Wi3[jt*32+(l&31)][w*64+mc*32+16h+4*(l>>5)+(e&3)+8*(e>>2)].
// Wi1posTb: bf16 pos_part transpose [64][512] (halves phase0 L2 read).
__global__ __launch_bounds__(256) void prep_kernel(
    const float* __restrict__ Wi2, const float* __restrict__ Wi3,
    const float* __restrict__ Wi1, const float* __restrict__ W1,
    const float* __restrict__ W2, const float* __restrict__ W3,
    ushort_t* __restrict__ Wi1posTb, ushort_t* __restrict__ W1b,
    ushort_t* __restrict__ W2b, ushort_t* __restrict__ W3b,
    ushort_t* __restrict__ Wi1sb, ushort_t* __restrict__ Wi2f32,
    ushort_t* __restrict__ Wi3g) {
  int idx = blockIdx.x * 256 + threadIdx.x;
  if (idx < 512 * 512) {
    W2b[idx] = f2bf(W2[idx]);
    // Wi2f32 frag-order scatter (dst-linear, coalesced writes)
    int j = idx & 7, lane = (idx >> 3) & 63;
    int ct = (idx >> 9) & 15, ks = idx >> 13;
    int c = ct * 32 + (lane & 31);
    int k = ks * 16 + (lane >> 5) * 8 + j;
    Wi2f32[idx] = f2bf(Wi2[c * 512 + k]);
  }
  if (idx < 64 * 512) {
    W3b[idx] = f2bf(W3[idx]);
    int p = idx >> 9, i = idx & 511;
    Wi1posTb[idx] = f2bf(Wi1[i * 128 + p]);   // pos_part[p][i] = Wi1[i][p], bf16
    // Wi3g dst-linear scatter
    int e = idx & 7, lane = (idx >> 3) & 63;
    int jt = (idx >> 9) & 1, h = (idx >> 10) & 1;
    int mc = (idx >> 11) & 1, w = idx >> 12;
    int jr = jt * 32 + (lane & 31);
    int c = w * 64 + mc * 32 + 16 * h + 4 * (lane >> 5) + (e & 3) + 8 * (e >> 2);
    Wi3g[idx] = f2bf(Wi3[jr * 512 + c]);
  }
  if (idx < 512 * 64) {
    W1b[idx] = f2bf(W1[idx]);                       // [512][64]
    int j = idx >> 6, k = idx & 63;
    Wi1sb[idx] = f2bf(Wi1[j * 128 + 64 + k]);       // shift cols of Wi1: [512][64]
  }
}

// ---------------- shift decoder, MFMA-batched: 16 rows/block ----------------
__global__ __launch_bounds__(256) void shift2_kernel(
    const float* __restrict__ shift_bits,
    const ushort_t* __restrict__ W1b, const float* __restrict__ b1,
    const float* __restrict__ g1, const float* __restrict__ be1,
    const ushort_t* __restrict__ W2b, const float* __restrict__ b2,
    const float* __restrict__ g2, const float* __restrict__ be2,
    const ushort_t* __restrict__ W3b, const float* __restrict__ b3,
    const ushort_t* __restrict__ Wi1sb, const float* __restrict__ bi1,
    float* __restrict__ sp) {
  __shared__ __align__(16) ushort_t hA[BT * 512];     // 16KB: h1 (post LN1+relu)
  __shared__ __align__(16) char reg2[32 * 1024];      // phase union
  __shared__ float b1s[512], g1s[512], be1s[512];
  __shared__ float b2s[512], g2s[512], be2s[512], bi1s[512];
  __shared__ float red[4][BT][2];
  __shared__ float b3s[64];

  ushort_t* sbt = (ushort_t*)reg2;                    // phase 1: shift_bits tile [16][64]
  ushort_t* Bs  = (ushort_t*)reg2;                    // phase 2: W2 tile [512][32]
  ushort_t* h2  = (ushort_t*)reg2;                    // phase 3: h2 [16][512]
  float (*lg32)[68] = (float(*)[68])(reg2 + 16 * 1024);
  ushort_t* sb2 = (ushort_t*)(reg2 + 16 * 1024 + 16 * 68 * 4);  // soft [16][64]

  int b0 = blockIdx.x * BT;
  int t = threadIdx.x, w = t >> 6, l = t & 63, lg = l >> 4, l15 = l & 15;

  b1s[t] = b1[t];  b1s[t + 256] = b1[t + 256];
  g1s[t] = g1[t];  g1s[t + 256] = g1[t + 256];
  be1s[t] = be1[t]; be1s[t + 256] = be1[t + 256];
  b2s[t] = b2[t];  b2s[t + 256] = b2[t + 256];
  g2s[t] = g2[t];  g2s[t + 256] = g2[t + 256];
  be2s[t] = be2[t]; be2s[t + 256] = be2[t + 256];
  bi1s[t] = bi1[t]; bi1s[t + 256] = bi1[t + 256];
  if (t < 64) b3s[t] = b3[t];
  if (t < 128) {   // stage shift_bits tile -> bf16 swizzled
    int row = t >> 3, g = t & 7;
    const float* src = shift_bits + (size_t)(b0 + row) * 64 + g * 8;
    uint4 pk;
    pk.x = (unsigned)f2bf(src[0]) | ((unsigned)f2bf(src[1]) << 16);
    pk.y = (unsigned)f2bf(src[2]) | ((unsigned)f2bf(src[3]) << 16);
    pk.z = (unsigned)f2bf(src[4]) | ((unsigned)f2bf(src[5]) << 16);
    pk.w = (unsigned)f2bf(src[6]) | ((unsigned)f2bf(src[7]) << 16);
    *(uint4*)((char*)sbt + ((row * 128 + g * 16) ^ ((row & 7) << 4))) = pk;
  }
  __syncthreads();

  // ----- GEMM1: x1[16][512] = sbt @ W1^T ; wave w owns cols [w*128, w*128+128) -----
  f32x4 acc[8];
#pragma unroll
  for (int nt = 0; nt < 8; ++nt) acc[nt] = (f32x4){0.f, 0.f, 0.f, 0.f};
#pragma unroll
  for (int ks = 0; ks < 2; ++ks) {
    bf16x8 af = *(const bf16x8*)((char*)sbt + ((l15 * 128 + ks * 64 + lg * 16) ^ ((l15 & 7) << 4)));
#pragma unroll
    for (int nt = 0; nt < 8; ++nt) {
      int c = w * 128 + nt * 16 + l15;
      bf16x8 bfr = *(const bf16x8*)(W1b + (size_t)c * 64 + ks * 32 + lg * 8);
      acc[nt] = __builtin_amdgcn_mfma_f32_16x16x32_bf16(af, bfr, acc[nt], 0, 0, 0);
    }
  }
  // ----- LN1 + relu -> hA -----
  {
    float s[4] = {0.f, 0.f, 0.f, 0.f}, q[4] = {0.f, 0.f, 0.f, 0.f};
#pragma unroll
    for (int nt = 0; nt < 8; ++nt) {
      int c = w * 128 + nt * 16 + l15;
      float bb = b1s[c];
#pragma unroll
      for (int r = 0; r < 4; ++r) {
        float x = acc[nt][r] + bb;
        acc[nt][r] = x;
        s[r] += x; q[r] += x * x;
      }
    }
#pragma unroll
    for (int m = 8; m >= 1; m >>= 1)
#pragma unroll
      for (int r = 0; r < 4; ++r) { s[r] += __shfl_xor(s[r], m); q[r] += __shfl_xor(q[r], m); }
    if (l15 == 0)
#pragma unroll
      for (int r = 0; r < 4; ++r) { red[w][4 * lg + r][0] = s[r]; red[w][4 * lg + r][1] = q[r]; }
    __syncthreads();
    float mean[4], rs[4];
#pragma unroll
    for (int r = 0; r < 4; ++r) {
      int p = 4 * lg + r;
      float S = red[0][p][0] + red[1][p][0] + red[2][p][0] + red[3][p][0];
      float Q = red[0][p][1] + red[1][p][1] + red[2][p][1] + red[3][p][1];
      mean[r] = S * (1.0f / 512.0f);
      float var = Q * (1.0f / 512.0f) - mean[r] * mean[r];
      rs[r] = rsqrtf(var + EPSV);
    }
#pragma unroll
    for (int nt = 0; nt < 8; ++nt) {
      int c = w * 128 + nt * 16 + l15;
      float gg = g1s[c], bb = be1s[c];
#pragma unroll
      for (int r = 0; r < 4; ++r) {
        int p = 4 * lg + r;
        float v = (acc[nt][r] - mean[r]) * rs[r] * gg + bb;
        v = v > 0.f ? v : 0.f;
        *(ushort_t*)((char*)hA + ((p * 1024 + c * 2) ^ ((p & 7) << 4))) = f2bf(v);
      }
    }
  }
  __syncthreads();

  // ----- GEMM2: x2[16][512] = hA @ W2^T, K=512 staged in 16 chunks of 32 -----
#pragma unroll
  for (int nt = 0; nt < 8; ++nt) acc[nt] = (f32x4){0.f, 0.f, 0.f, 0.f};
  for (int step = 0; step < 16; ++step) {
    int i0 = step * 32;
#pragma unroll
    for (int qq = 0; qq < 8; ++qq) {   // stage Bs [512][32] swizzled (linear writes)
      int g = qq * 256 + t;
      int c = g >> 2, xg = g & 3;
      int ic = xg ^ ((c >> 1) & 3);
      ((uint4*)Bs)[g] = *(const uint4*)(W2b + (size_t)c * 512 + i0 + ic * 8);
    }
    __syncthreads();
    bf16x8 af = *(const bf16x8*)((char*)hA + ((l15 * 1024 + step * 64 + lg * 16) ^ ((l15 & 7) << 4)));
#pragma unroll
    for (int nt = 0; nt < 8; ++nt) {
      int c = w * 128 + nt * 16 + l15;
      bf16x8 bfr = ((const bf16x8*)Bs)[c * 4 + (lg ^ ((c >> 1) & 3))];
      acc[nt] = __builtin_amdgcn_mfma_f32_16x16x32_bf16(af, bfr, acc[nt], 0, 0, 0);
    }
    __syncthreads();
  }
  // ----- LN2 + relu -> h2 (overwrites Bs region; safe: barrier above) -----
  {
    float s[4] = {0.f, 0.f, 0.f, 0.f}, q[4] = {0.f, 0.f, 0.f, 0.f};
#pragma unroll
    for (int nt = 0; nt < 8; ++nt) {
      int c = w * 128 + nt * 16 + l15;
      float bb = b2s[c];
#pragma unroll
      for (int r = 0; r < 4; ++r) {
        float x = acc[nt][r] + bb;
        acc[nt][r] = x;
        s[r] += x; q[r] += x * x;
      }
    }
#pragma unroll
    for (int m = 8; m >= 1; m >>= 1)
#pragma unroll
      for (int r = 0; r < 4; ++r) { s[r] += __shfl_xor(s[r], m); q[r] += __shfl_xor(q[r], m); }
    if (l15 == 0)
#pragma unroll
      for (int r = 0; r < 4; ++r) { red[w][4 * lg + r][0] = s[r]; red[w][4 * lg + r][1] = q[r]; }
    __syncthreads();
    float mean[4], rs[4];
#pragma unroll
    for (int r = 0; r < 4; ++r) {
      int p = 4 * lg + r;
      float S = red[0][p][0] + red[1][p][0] + red[2][p][0] + red[3][p][0];
      float Q = red[0][p][1] + red[1][p][1] + red[2][p][1] + red[3][p][1];
      mean[r] = S * (1.0f / 512.0f);
      float var = Q * (1.0f / 512.0f) - mean[r] * mean[r];
      rs[r] = rsqrtf(var + EPSV);
    }
#pragma unroll
    for (int nt = 0; nt < 8; ++nt) {
      int c = w * 128 + nt * 16 + l15;
      float gg = g2s[c], bb = be2s[c];
#pragma unroll
      for (int r = 0; r < 4; ++r) {
        int p = 4 * lg + r;
        float v = (acc[nt][r] - mean[r]) * rs[r] * gg + bb;
        v = v > 0.f ? v : 0.f;
        *(ushort_t*)((char*)h2 + ((p * 1024 + c * 2) ^ ((p & 7) << 4))) = f2bf(v);
      }
    }
  }
  __syncthreads();

  // ----- GEMM3: logits[16][64] = h2 @ W3^T ; wave w owns cols [16w,16w+16) -----
  {
    f32x4 a3 = (f32x4){0.f, 0.f, 0.f, 0.f};
#pragma unroll
    for (int ks = 0; ks < 16; ++ks) {
      bf16x8 af = *(const bf16x8*)((char*)h2 + ((l15 * 1024 + ks * 64 + lg * 16) ^ ((l15 & 7) << 4)));
      bf16x8 bfr = *(const bf16x8*)(W3b + (size_t)(w * 16 + l15) * 512 + ks * 32 + lg * 8);
      a3 = __builtin_amdgcn_mfma_f32_16x16x32_bf16(af, bfr, a3, 0, 0, 0);
    }
    int c = w * 16 + l15;
    float bb = b3s[c];
#pragma unroll
    for (int r = 0; r < 4; ++r) lg32[4 * lg + r][c] = a3[r] + bb;
  }
  __syncthreads();

  // ----- softmax over 64 logits -> sb2 (bf16, swizzled) -----
  {
    int r = t >> 4, j = t & 15;
    float v[4];
    float m = -1e30f;
#pragma unroll
    for (int mq = 0; mq < 4; ++mq) { v[mq] = lg32[r][mq * 16 + j]; m = fmaxf(m, v[mq]); }
#pragma unroll
    for (int mk = 8; mk >= 1; mk >>= 1) m = fmaxf(m, __shfl_xor(m, mk));
    float ssum = 0.f;
#pragma unroll
    for (int mq = 0; mq < 4; ++mq) { v[mq] = expf(v[mq] - m); ssum += v[mq]; }
#pragma unroll
    for (int mk = 8; mk >= 1; mk >>= 1) ssum += __shfl_xor(ssum, mk);
    float inv = 1.f / ssum;
#pragma unroll
    for (int mq = 0; mq < 4; ++mq) {
      int c = mq * 16 + j;
      *(ushort_t*)((char*)sb2 + ((r * 128 + c * 2) ^ ((r & 7) << 4))) = f2bf(v[mq] * inv);
    }
  }
  __syncthreads();

  // ----- GEMM4: sp[16][512] = soft @ Wi1shift^T + bi1 -----
  {
    f32x4 a4[8];
#pragma unroll
    for (int nt = 0; nt < 8; ++nt) a4[nt] = (f32x4){0.f, 0.f, 0.f, 0.f};
#pragma unroll
    for (int ks = 0; ks < 2; ++ks) {
      bf16x8 af = *(const bf16x8*)((char*)sb2 + ((l15 * 128 + ks * 64 + lg * 16) ^ ((l15 & 7) << 4)));
#pragma unroll
      for (int nt = 0; nt < 8; ++nt) {
        int c = w * 128 + nt * 16 + l15;
        bf16x8 bfr = *(const bf16x8*)(Wi1sb + (size_t)c * 64 + ks * 32 + lg * 8);
        a4[nt] = __builtin_amdgcn_mfma_f32_16x16x32_bf16(af, bfr, a4[nt], 0, 0, 0);
      }
    }
#pragma unroll
    for (int nt = 0; nt < 8; ++nt) {
      int c = w * 128 + nt * 16 + l15;
      float bb = bi1s[c];
#pragma unroll
      for (int r = 0; r < 4; ++r)
        sp[(size_t)(b0 + 4 * lg + r) * 512 + c] = a4[nt][r] + bb;
    }
  }
}

// ---------------- big8: in-reg GEMM1->GEMM2 fusion, NON-ATOMIC staged reduction ----
// BM=64 (1 batch row), BN=512, 8 waves. h1[64][512] LDS (&15 swizzle), bf16 posT.
// GEMM1 = mfma(Wi2frag, h1frag) (reg<->c, lane<->p), depth-4 B prefetch.
// h2 stays in regs: relu+bias, cvt_pk to bf16 A-frags (layout verified R8).
// GEMM2 = mfma(h2frag, Wi3gfrag) fully in-reg, all 8 waves (K split per wave).
// Reduction: waves 0-3 store f32 partials to 4 disjoint 16KB regions
// (transposed [c][r], XOR swizzle r^=(c&7)<<3 -> b128 stores, conflict-free);
// barrier; waves 4-7 RMW-add (race-free). Max-free softmax sums 4 regions.
__global__ __launch_bounds__(512, 4) void big8_kernel(
    const float* __restrict__ a_bits, const float* __restrict__ sp,
    const ushort_t* __restrict__ posTb,
    const ushort_t* __restrict__ Wi2f32, const ushort_t* __restrict__ Wi3g,
    const float* __restrict__ bi2, const float* __restrict__ bi3,
    float* __restrict__ out) {
  __shared__ __align__(16) ushort_t h1s[64 * 512];   // 64KB; reused as 4x16KB f32 partials
  __shared__ float bi2s[512];
  __shared__ float ab[64];
  __shared__ float bi3s[64];

  int b = blockIdx.x, t = threadIdx.x;
  int w = t >> 6, l = t & 63;
  int l31 = l & 31, hi = l >> 5;

  bi2s[t] = bi2[t];
  if (t < 64) { ab[t] = a_bits[b * 64 + t]; bi3s[t] = bi3[t]; }

  // ---- phase 0: h1[64][512] = relu(sp[b] + pos) -> LDS bf16, swizzled, ONCE ----
  {
    const float* sprow = sp + (size_t)b * 512 + l * 8;
    float4 s0 = *(const float4*)(sprow);
    float4 s1 = *(const float4*)(sprow + 4);
#pragma unroll
    for (int g = 0; g < 8; ++g) {
      int p = g * 8 + w;                    // wave w covers rows {w, 8+w, ..., 56+w}
      bf16x8 pr = *(const bf16x8*)(posTb + (size_t)p * 512 + l * 8);
      float v0 = fmaxf(s0.x + bf2f(pr[0]), 0.f), v1 = fmaxf(s0.y + bf2f(pr[1]), 0.f);
      float v2 = fmaxf(s0.z + bf2f(pr[2]), 0.f), v3 = fmaxf(s0.w + bf2f(pr[3]), 0.f);
      float v4 = fmaxf(s1.x + bf2f(pr[4]), 0.f), v5 = fmaxf(s1.y + bf2f(pr[5]), 0.f);
      float v6 = fmaxf(s1.z + bf2f(pr[6]), 0.f), v7 = fmaxf(s1.w + bf2f(pr[7]), 0.f);
      uint4 pk;
      pk.x = pack2bf(v0, v1); pk.y = pack2bf(v2, v3);
      pk.z = pack2bf(v4, v5); pk.w = pack2bf(v6, v7);
      *(uint4*)((char*)h1s + ((p * 1024 + l * 16) ^ ((p & 15) << 4))) = pk;
    }
  }
  __syncthreads();

  // ---- GEMM1: mfma(Wi2, h1) ; 32x32x16, depth-4 B prefetch, barrier-free ----
  f32x16 acc[2][2];   // acc[mc][np]: reg<->c (c-tile mc), lane<->p (p-tile np)
#pragma unroll
  for (int mc = 0; mc < 2; ++mc)
#pragma unroll
    for (int np = 0; np < 2; ++np)
#pragma unroll
      for (int r = 0; r < 16; ++r) acc[mc][np][r] = 0.f;

  {
    const bf16x8* bbase = (const bf16x8*)Wi2f32 + ((size_t)(2 * w) * 64 + l);
    bf16x8 wf[4][2];
#pragma unroll
    for (int d = 0; d < 4; ++d) {
      wf[d][0] = bbase[(size_t)d * 1024];
      wf[d][1] = bbase[(size_t)d * 1024 + 64];
    }
    for (int kb = 0; kb < 8; ++kb) {
#pragma unroll
      for (int d = 0; d < 4; ++d) {
        int ks = kb * 4 + d;
        bf16x8 w0 = wf[d][0], w1 = wf[d][1];
        if (kb < 7) {
          wf[d][0] = bbase[(size_t)(ks + 4) * 1024];
          wf[d][1] = bbase[(size_t)(ks + 4) * 1024 + 64];
        }
        int row0 = l31, row1 = 32 + l31;
        bf16x8 h0 = *(const bf16x8*)((char*)h1s + ((row0 * 1024 + ks * 32 + hi * 16) ^ ((row0 & 15) << 4)));
        bf16x8 h1v = *(const bf16x8*)((char*)h1s + ((row1 * 1024 + ks * 32 + hi * 16) ^ ((row1 & 15) << 4)));
        acc[0][0] = __builtin_amdgcn_mfma_f32_32x32x16_bf16(w0, h0, acc[0][0], 0, 0, 0);
        acc[0][1] = __builtin_amdgcn_mfma_f32_32x32x16_bf16(w0, h1v, acc[0][1], 0, 0, 0);
        acc[1][0] = __builtin_amdgcn_mfma_f32_32x32x16_bf16(w1, h0, acc[1][0], 0, 0, 0);
        acc[1][1] = __builtin_amdgcn_mfma_f32_32x32x16_bf16(w1, h1v, acc[1][1], 0, 0, 0);
      }
    }
  }

  // ---- h2 = relu(acc + bi2), pack to bf16 A-frags in regs (layout verified R8) ----
  bf16x8 pkf[2][2][2];   // [np][mc][h]
#pragma unroll
  for (int mc = 0; mc < 2; ++mc) {
    float bia[16];
#pragma unroll
    for (int rq = 0; rq < 4; ++rq) {
      int c0 = w * 64 + mc * 32 + 8 * rq + 4 * hi;
      float4 bi4 = *(const float4*)(bi2s + c0);
      bia[4 * rq + 0] = bi4.x; bia[4 * rq + 1] = bi4.y;
      bia[4 * rq + 2] = bi4.z; bia[4 * rq + 3] = bi4.w;
    }
#pragma unroll
    for (int np = 0; np < 2; ++np) {
      float hv[16];
#pragma unroll
      for (int r = 0; r < 16; ++r) hv[r] = fmaxf(acc[mc][np][r] + bia[r], 0.f);
#pragma unroll
      for (int h = 0; h < 2; ++h) {
        unsigned d0 = pack2bf(hv[8 * h + 0], hv[8 * h + 1]);
        unsigned d1 = pack2bf(hv[8 * h + 2], hv[8 * h + 3]);
        unsigned d2 = pack2bf(hv[8 * h + 4], hv[8 * h + 5]);
        unsigned d3 = pack2bf(hv[8 * h + 6], hv[8 * h + 7]);
        union { unsigned u[4]; bf16x8 v; } cv;
        cv.u[0] = d0; cv.u[1] = d1; cv.u[2] = d2; cv.u[3] = d3;
        pkf[np][mc][h] = cv.v;
      }
    }
  }
  __syncthreads();   // all waves done reading h1s -> safe to reuse as partials

  // ---- GEMM2: partial logits over this wave's 64-c chunk, fully in-reg ----
  f32x16 l00, l01, l10, l11;
#pragma unroll
  for (int r = 0; r < 16; ++r) { l00[r] = 0.f; l01[r] = 0.f; l10[r] = 0.f; l11[r] = 0.f; }
  {
    const bf16x8* gbase = (const bf16x8*)Wi3g + ((size_t)w * 8 * 64 + l);
#pragma unroll
    for (int mc = 0; mc < 2; ++mc) {
#pragma unroll
      for (int h = 0; h < 2; ++h) {
        bf16x8 g0 = gbase[((mc * 2 + h) * 2 + 0) * 64];
        bf16x8 g1 = gbase[((mc * 2 + h) * 2 + 1) * 64];
        l00 = __builtin_amdgcn_mfma_f32_32x32x16_bf16(pkf[0][mc][h], g0, l00, 0, 0, 0);
        l01 = __builtin_amdgcn_mfma_f32_32x32x16_bf16(pkf[0][mc][h], g1, l01, 0, 0, 0);
        l10 = __builtin_amdgcn_mfma_f32_32x32x16_bf16(pkf[1][mc][h], g0, l10, 0, 0, 0);
        l11 = __builtin_amdgcn_mfma_f32_32x32x16_bf16(pkf[1][mc][h], g1, l11, 0, 0, 0);
      }
    }
  }

  // ---- staged reduction: transposed P[c][r], r ^= (c&7)<<3, b128 ops ----
  // D: lane<->j col (jt*32+l31), reg<->p row (np*32 + (r&3)+8*(r>>2)+4*hi)
  float* Lg = (float*)h1s;
  if (w < 4) {
    float* Lq = Lg + w * 4096;
#pragma unroll
    for (int rq = 0; rq < 4; ++rq) {
      int rb = 8 * rq + 4 * hi;
      int cA = l31, cB = 32 + l31;
      *(float4*)(Lq + cA * 64 + (rb ^ ((cA & 7) << 3))) =
          make_float4(l00[4*rq], l00[4*rq+1], l00[4*rq+2], l00[4*rq+3]);
      *(float4*)(Lq + cB * 64 + (rb ^ ((cB & 7) << 3))) =
          make_float4(l01[4*rq], l01[4*rq+1], l01[4*rq+2], l01[4*rq+3]);
      *(float4*)(Lq + cA * 64 + ((rb + 32) ^ ((cA & 7) << 3))) =
          make_float4(l10[4*rq], l10[4*rq+1], l10[4*rq+2], l10[4*rq+3]);
      *(float4*)(Lq + cB * 64 + ((rb + 32) ^ ((cB & 7) << 3))) =
          make_float4(l11[4*rq], l11[4*rq+1], l11[4*rq+2], l11[4*rq+3]);
    }
  }
  __syncthreads();
  if (w >= 4) {
    float* Lq = Lg + (w - 4) * 4096;
#pragma unroll
    for (int rq = 0; rq < 4; ++rq) {
      int rb = 8 * rq + 4 * hi;
      int cA = l31, cB = 32 + l31;
      float* pA0 = Lq + cA * 64 + (rb ^ ((cA & 7) << 3));
      float* pB0 = Lq + cB * 64 + (rb ^ ((cB & 7) << 3));
      float* pA1 = Lq + cA * 64 + ((rb + 32) ^ ((cA & 7) << 3));
      float* pB1 = Lq + cB * 64 + ((rb + 32) ^ ((cB & 7) << 3));
      float4 oA0 = *(float4*)pA0, oB0 = *(float4*)pB0;
      float4 oA1 = *(float4*)pA1, oB1 = *(float4*)pB1;
      oA0.x += l00[4*rq]; oA0.y += l00[4*rq+1]; oA0.z += l00[4*rq+2]; oA0.w += l00[4*rq+3];
      oB0.x += l01[4*rq]; oB0.y += l01[4*rq+1]; oB0.z += l01[4*rq+2]; oB0.w += l01[4*rq+3];
      oA1.x += l10[4*rq]; oA1.y += l10[4*rq+1]; oA1.z += l10[4*rq+2]; oA1.w += l10[4*rq+3];
      oB1.x += l11[4*rq]; oB1.y += l11[4*rq+1]; oB1.z += l11[4*rq+2]; oB1.w += l11[4*rq+3];
      *(float4*)pA0 = oA0; *(float4*)pB0 = oB0;
      *(float4*)pA1 = oA1; *(float4*)pB1 = oB1;
    }
  }
  __syncthreads();

  // ---- max-free softmax + gather (verified R8: logits tiny, exp safe) ----
  {
    int p = t >> 3, jo = t & 7;
    float s = 0.f, g = 0.f;
#pragma unroll
    for (int m = 0; m < 8; ++m) {
      int c = jo * 8 + m;
      int off = c * 64 + (p ^ ((c & 7) << 3));
      float lv = bi3s[c] + Lg[off] + Lg[4096 + off] + Lg[8192 + off] + Lg[12288 + off];
      float e = __expf(lv);
      s += e; g += e * ab[c];
    }
#pragma unroll
    for (int mm = 4; mm >= 1; mm >>= 1) { s += __shfl_xor(s, mm); g += __shfl_xor(g, mm); }
    if (jo == 0) out[b * 64 + p] = g / s;
  }
}

extern "C" void kernel_launch(void* const* d_in, const int* in_sizes, int n_in,
                              void* d_out, int out_size, void* d_ws, size_t ws_size,
                              hipStream_t stream) {
  const float* a_bits     = (const float*)d_in[0];
  const float* shift_bits = (const float*)d_in[1];
  const float* W1  = (const float*)d_in[2];
  const float* b1  = (const float*)d_in[3];
  const float* g1  = (const float*)d_in[4];
  const float* be1 = (const float*)d_in[5];
  const float* W2  = (const float*)d_in[6];
  const float* b2  = (const float*)d_in[7];
  const float* g2  = (const float*)d_in[8];
  const float* be2 = (const float*)d_in[9];
  const float* W3  = (const float*)d_in[10];
  const float* b3  = (const float*)d_in[11];
  const float* Wi1 = (const float*)d_in[12];
  const float* bi1 = (const float*)d_in[13];
  const float* Wi2 = (const float*)d_in[14];
  const float* bi2 = (const float*)d_in[15];
  const float* Wi3 = (const float*)d_in[16];
  const float* bi3 = (const float*)d_in[17];
  float* out = (float*)d_out;

  // ws layout: sp fp32 [B][512] (8MB) | W2b (512KB) | W1b (64KB) | W3b (64KB)
  //            | Wi1sb (64KB) | Wi1posTb bf16 (64KB) | Wi2f32 (512KB) | Wi3g (64KB)
  float* sp = (float*)d_ws;
  ushort_t* W2b = (ushort_t*)((char*)d_ws + (size_t)B_N * HID * 4);
  ushort_t* W1b = W2b + 512 * 512;
  ushort_t* W3b = W1b + 512 * 64;
  ushort_t* Wi1sb = W3b + 64 * 512;
  ushort_t* Wi1posTb = Wi1sb + 512 * 64;
  ushort_t* Wi2f32 = Wi1posTb + 64 * 512;
  ushort_t* Wi3g = Wi2f32 + 512 * 512;

  prep_kernel<<<1024, 256, 0, stream>>>(Wi2, Wi3, Wi1, W1, W2, W3,
                                        Wi1posTb, W1b, W2b, W3b, Wi1sb, Wi2f32, Wi3g);
  shift2_kernel<<<B_N / BT, 256, 0, stream>>>(shift_bits, W1b, b1, g1, be1,
                                              W2b, b2, g2, be2, W3b, b3, Wi1sb, bi1, sp);
  big8_kernel<<<B_N, 512, 0, stream>>>(a_bits, sp, Wi1posTb, Wi2f32, Wi3g, bi2, bi3, out);
}

// Round 10
// 202.237 us; speedup vs baseline: 4.0482x; 1.0104x over previous
//
#include <hip/hip_runtime.h>
#include <hip/hip_bf16.h>
#include <math.h>

// Problem constants
#define B_N 4096
#define BITSN 64
#define HID 512
#define EPSV 1e-5f
#define BT 16   // batch rows per shift2 block

typedef unsigned short ushort_t;
typedef __attribute__((ext_vector_type(8))) short bf16x8;
typedef __attribute__((ext_vector_type(4))) float f32x4;
typedef __attribute__((ext_vector_type(16))) float f32x16;

__device__ __forceinline__ ushort_t f2bf(float f) {
  unsigned u = __float_as_uint(f);
  u += 0x7FFF + ((u >> 16) & 1);   // round-to-nearest-even
  return (ushort_t)(u >> 16);
}

__device__ __forceinline__ unsigned pack2bf(float lo, float hi) {
  union { __hip_bfloat162 h; unsigned u; } cv;
  cv.h = __float22bfloat162_rn(make_float2(lo, hi));  // v_cvt_pk_bf16_f32
  return cv.u;
}

__device__ __forceinline__ float bf2f(short v) {
  return __uint_as_float(((unsigned)(unsigned short)v) << 16);
}

// ---------------- prep: bf16 copies, transposes, FRAGMENT-ORDER weights ----
// Wi2f32: 32x32x16 frag order (big GEMM1 B). Frag (ks 0..31, ct 0..15) lane l:
//   Wi2[ct*32 + (l&31)][ks*16 + (l>>5)*8 + j].
// W2f: 16x16x32 frag order (shift2 GEMM2 B, same mapping verified in R5):
//   idx=((ks*32+ct)*64+lane)*8+j -> W2[ct*16+(lane&15)][ks*32+(lane>>4)*8+j].
// Wi3g: big GEMM2 B in the (e,hi)->c permutation the in-register h2 pack
//   produces (verified R8).
// Wi1posTb: bf16 pos_part transpose [64][512].
__global__ __launch_bounds__(256) void prep_kernel(
    const float* __restrict__ Wi2, const float* __restrict__ Wi3,
    const float* __restrict__ Wi1, const float* __restrict__ W1,
    const float* __restrict__ W2, const float* __restrict__ W3,
    ushort_t* __restrict__ Wi1posTb, ushort_t* __restrict__ W1b,
    ushort_t* __restrict__ W2f, ushort_t* __restrict__ W3b,
    ushort_t* __restrict__ Wi1sb, ushort_t* __restrict__ Wi2f32,
    ushort_t* __restrict__ Wi3g) {
  int idx = blockIdx.x * 256 + threadIdx.x;
  if (idx < 512 * 512) {
    // W2f (16x16x32 frag order) for shift2 GEMM2
    {
      int j = idx & 7, lane = (idx >> 3) & 63;
      int ct = (idx >> 9) & 31, ks = idx >> 14;
      int c = ct * 16 + (lane & 15);
      int k = ks * 32 + (lane >> 4) * 8 + j;
      W2f[idx] = f2bf(W2[c * 512 + k]);
    }
    // Wi2f32 (32x32x16 frag order) for big GEMM1
    {
      int j = idx & 7, lane = (idx >> 3) & 63;
      int ct = (idx >> 9) & 15, ks = idx >> 13;
      int c = ct * 32 + (lane & 31);
      int k = ks * 16 + (lane >> 5) * 8 + j;
      Wi2f32[idx] = f2bf(Wi2[c * 512 + k]);
    }
  }
  if (idx < 64 * 512) {
    W3b[idx] = f2bf(W3[idx]);
    int p = idx >> 9, i = idx & 511;
    Wi1posTb[idx] = f2bf(Wi1[i * 128 + p]);   // pos_part[p][i] = Wi1[i][p], bf16
    // Wi3g dst-linear scatter
    int e = idx & 7, lane = (idx >> 3) & 63;
    int jt = (idx >> 9) & 1, h = (idx >> 10) & 1;
    int mc = (idx >> 11) & 1, w = idx >> 12;
    int jr = jt * 32 + (lane & 31);
    int c = w * 64 + mc * 32 + 16 * h + 4 * (lane >> 5) + (e & 3) + 8 * (e >> 2);
    Wi3g[idx] = f2bf(Wi3[jr * 512 + c]);
  }
  if (idx < 512 * 64) {
    W1b[idx] = f2bf(W1[idx]);                       // [512][64]
    int j = idx >> 6, k = idx & 63;
    Wi1sb[idx] = f2bf(Wi1[j * 128 + 64 + k]);       // shift cols of Wi1: [512][64]
  }
}

// ---------------- shift decoder, MFMA-batched: 16 rows/block ----------------
// GEMM2 now barrier-free with frag-order W2f (B direct from L2).
__global__ __launch_bounds__(256) void shift2_kernel(
    const float* __restrict__ shift_bits,
    const ushort_t* __restrict__ W1b, const float* __restrict__ b1,
    const float* __restrict__ g1, const float* __restrict__ be1,
    const ushort_t* __restrict__ W2f, const float* __restrict__ b2,
    const float* __restrict__ g2, const float* __restrict__ be2,
    const ushort_t* __restrict__ W3b, const float* __restrict__ b3,
    const ushort_t* __restrict__ Wi1sb, const float* __restrict__ bi1,
    float* __restrict__ sp) {
  __shared__ __align__(16) ushort_t hA[BT * 512];     // 16KB: h1 (post LN1+relu)
  __shared__ __align__(16) char reg2[32 * 1024];      // phase union
  __shared__ float b1s[512], g1s[512], be1s[512];
  __shared__ float b2s[512], g2s[512], be2s[512], bi1s[512];
  __shared__ float red[4][BT][2];
  __shared__ float b3s[64];

  ushort_t* sbt = (ushort_t*)reg2;                    // phase 1: shift_bits tile [16][64]
  ushort_t* h2  = (ushort_t*)reg2;                    // phase 3: h2 [16][512]
  float (*lg32)[68] = (float(*)[68])(reg2 + 16 * 1024);
  ushort_t* sb2 = (ushort_t*)(reg2 + 16 * 1024 + 16 * 68 * 4);  // soft [16][64]

  int b0 = blockIdx.x * BT;
  int t = threadIdx.x, w = t >> 6, l = t & 63, lg = l >> 4, l15 = l & 15;

  b1s[t] = b1[t];  b1s[t + 256] = b1[t + 256];
  g1s[t] = g1[t];  g1s[t + 256] = g1[t + 256];
  be1s[t] = be1[t]; be1s[t + 256] = be1[t + 256];
  b2s[t] = b2[t];  b2s[t + 256] = b2[t + 256];
  g2s[t] = g2[t];  g2s[t + 256] = g2[t + 256];
  be2s[t] = be2[t]; be2s[t + 256] = be2[t + 256];
  bi1s[t] = bi1[t]; bi1s[t + 256] = bi1[t + 256];
  if (t < 64) b3s[t] = b3[t];
  if (t < 128) {   // stage shift_bits tile -> bf16 swizzled
    int row = t >> 3, g = t & 7;
    const float* src = shift_bits + (size_t)(b0 + row) * 64 + g * 8;
    uint4 pk;
    pk.x = (unsigned)f2bf(src[0]) | ((unsigned)f2bf(src[1]) << 16);
    pk.y = (unsigned)f2bf(src[2]) | ((unsigned)f2bf(src[3]) << 16);
    pk.z = (unsigned)f2bf(src[4]) | ((unsigned)f2bf(src[5]) << 16);
    pk.w = (unsigned)f2bf(src[6]) | ((unsigned)f2bf(src[7]) << 16);
    *(uint4*)((char*)sbt + ((row * 128 + g * 16) ^ ((row & 7) << 4))) = pk;
  }
  __syncthreads();

  // ----- GEMM1: x1[16][512] = sbt @ W1^T ; wave w owns cols [w*128, w*128+128) -----
  f32x4 acc[8];
#pragma unroll
  for (int nt = 0; nt < 8; ++nt) acc[nt] = (f32x4){0.f, 0.f, 0.f, 0.f};
#pragma unroll
  for (int ks = 0; ks < 2; ++ks) {
    bf16x8 af = *(const bf16x8*)((char*)sbt + ((l15 * 128 + ks * 64 + lg * 16) ^ ((l15 & 7) << 4)));
#pragma unroll
    for (int nt = 0; nt < 8; ++nt) {
      int c = w * 128 + nt * 16 + l15;
      bf16x8 bfr = *(const bf16x8*)(W1b + (size_t)c * 64 + ks * 32 + lg * 8);
      acc[nt] = __builtin_amdgcn_mfma_f32_16x16x32_bf16(af, bfr, acc[nt], 0, 0, 0);
    }
  }
  // ----- LN1 + relu -> hA -----
  {
    float s[4] = {0.f, 0.f, 0.f, 0.f}, q[4] = {0.f, 0.f, 0.f, 0.f};
#pragma unroll
    for (int nt = 0; nt < 8; ++nt) {
      int c = w * 128 + nt * 16 + l15;
      float bb = b1s[c];
#pragma unroll
      for (int r = 0; r < 4; ++r) {
        float x = acc[nt][r] + bb;
        acc[nt][r] = x;
        s[r] += x; q[r] += x * x;
      }
    }
#pragma unroll
    for (int m = 8; m >= 1; m >>= 1)
#pragma unroll
      for (int r = 0; r < 4; ++r) { s[r] += __shfl_xor(s[r], m); q[r] += __shfl_xor(q[r], m); }
    if (l15 == 0)
#pragma unroll
      for (int r = 0; r < 4; ++r) { red[w][4 * lg + r][0] = s[r]; red[w][4 * lg + r][1] = q[r]; }
    __syncthreads();
    float mean[4], rs[4];
#pragma unroll
    for (int r = 0; r < 4; ++r) {
      int p = 4 * lg + r;
      float S = red[0][p][0] + red[1][p][0] + red[2][p][0] + red[3][p][0];
      float Q = red[0][p][1] + red[1][p][1] + red[2][p][1] + red[3][p][1];
      mean[r] = S * (1.0f / 512.0f);
      float var = Q * (1.0f / 512.0f) - mean[r] * mean[r];
      rs[r] = rsqrtf(var + EPSV);
    }
#pragma unroll
    for (int nt = 0; nt < 8; ++nt) {
      int c = w * 128 + nt * 16 + l15;
      float gg = g1s[c], bb = be1s[c];
#pragma unroll
      for (int r = 0; r < 4; ++r) {
        int p = 4 * lg + r;
        float v = (acc[nt][r] - mean[r]) * rs[r] * gg + bb;
        v = v > 0.f ? v : 0.f;
        *(ushort_t*)((char*)hA + ((p * 1024 + c * 2) ^ ((p & 7) << 4))) = f2bf(v);
      }
    }
  }
  __syncthreads();

  // ----- GEMM2: x2[16][512] = hA @ W2^T, frag-order W2f, barrier-free -----
#pragma unroll
  for (int nt = 0; nt < 8; ++nt) acc[nt] = (f32x4){0.f, 0.f, 0.f, 0.f};
  {
    const bf16x8* w2base = (const bf16x8*)W2f + ((size_t)(w * 8) * 64 + l);
#pragma unroll 2
    for (int step = 0; step < 16; ++step) {
      bf16x8 af = *(const bf16x8*)((char*)hA + ((l15 * 1024 + step * 64 + lg * 16) ^ ((l15 & 7) << 4)));
#pragma unroll
      for (int nt = 0; nt < 8; ++nt) {
        bf16x8 bfr = w2base[((size_t)step * 32 + nt) * 64];
        acc[nt] = __builtin_amdgcn_mfma_f32_16x16x32_bf16(af, bfr, acc[nt], 0, 0, 0);
      }
    }
  }
  __syncthreads();   // hA reads done; h2 region (reg2) free for overwrite
  // ----- LN2 + relu -> h2 -----
  {
    float s[4] = {0.f, 0.f, 0.f, 0.f}, q[4] = {0.f, 0.f, 0.f, 0.f};
#pragma unroll
    for (int nt = 0; nt < 8; ++nt) {
      int c = w * 128 + nt * 16 + l15;
      float bb = b2s[c];
#pragma unroll
      for (int r = 0; r < 4; ++r) {
        float x = acc[nt][r] + bb;
        acc[nt][r] = x;
        s[r] += x; q[r] += x * x;
      }
    }
#pragma unroll
    for (int m = 8; m >= 1; m >>= 1)
#pragma unroll
      for (int r = 0; r < 4; ++r) { s[r] += __shfl_xor(s[r], m); q[r] += __shfl_xor(q[r], m); }
    if (l15 == 0)
#pragma unroll
      for (int r = 0; r < 4; ++r) { red[w][4 * lg + r][0] = s[r]; red[w][4 * lg + r][1] = q[r]; }
    __syncthreads();
    float mean[4], rs[4];
#pragma unroll
    for (int r = 0; r < 4; ++r) {
      int p = 4 * lg + r;
      float S = red[0][p][0] + red[1][p][0] + red[2][p][0] + red[3][p][0];
      float Q = red[0][p][1] + red[1][p][1] + red[2][p][1] + red[3][p][1];
      mean[r] = S * (1.0f / 512.0f);
      float var = Q * (1.0f / 512.0f) - mean[r] * mean[r];
      rs[r] = rsqrtf(var + EPSV);
    }
#pragma unroll
    for (int nt = 0; nt < 8; ++nt) {
      int c = w * 128 + nt * 16 + l15;
      float gg = g2s[c], bb = be2s[c];
#pragma unroll
      for (int r = 0; r < 4; ++r) {
        int p = 4 * lg + r;
        float v = (acc[nt][r] - mean[r]) * rs[r] * gg + bb;
        v = v > 0.f ? v : 0.f;
        *(ushort_t*)((char*)h2 + ((p * 1024 + c * 2) ^ ((p & 7) << 4))) = f2bf(v);
      }
    }
  }
  __syncthreads();

  // ----- GEMM3: logits[16][64] = h2 @ W3^T ; wave w owns cols [16w,16w+16) -----
  {
    f32x4 a3 = (f32x4){0.f, 0.f, 0.f, 0.f};
#pragma unroll
    for (int ks = 0; ks < 16; ++ks) {
      bf16x8 af = *(const bf16x8*)((char*)h2 + ((l15 * 1024 + ks * 64 + lg * 16) ^ ((l15 & 7) << 4)));
      bf16x8 bfr = *(const bf16x8*)(W3b + (size_t)(w * 16 + l15) * 512 + ks * 32 + lg * 8);
      a3 = __builtin_amdgcn_mfma_f32_16x16x32_bf16(af, bfr, a3, 0, 0, 0);
    }
    int c = w * 16 + l15;
    float bb = b3s[c];
#pragma unroll
    for (int r = 0; r < 4; ++r) lg32[4 * lg + r][c] = a3[r] + bb;
  }
  __syncthreads();

  // ----- softmax over 64 logits -> sb2 (bf16, swizzled) -----
  {
    int r = t >> 4, j = t & 15;
    float v[4];
    float m = -1e30f;
#pragma unroll
    for (int mq = 0; mq < 4; ++mq) { v[mq] = lg32[r][mq * 16 + j]; m = fmaxf(m, v[mq]); }
#pragma unroll
    for (int mk = 8; mk >= 1; mk >>= 1) m = fmaxf(m, __shfl_xor(m, mk));
    float ssum = 0.f;
#pragma unroll
    for (int mq = 0; mq < 4; ++mq) { v[mq] = expf(v[mq] - m); ssum += v[mq]; }
#pragma unroll
    for (int mk = 8; mk >= 1; mk >>= 1) ssum += __shfl_xor(ssum, mk);
    float inv = 1.f / ssum;
#pragma unroll
    for (int mq = 0; mq < 4; ++mq) {
      int c = mq * 16 + j;
      *(ushort_t*)((char*)sb2 + ((r * 128 + c * 2) ^ ((r & 7) << 4))) = f2bf(v[mq] * inv);
    }
  }
  __syncthreads();

  // ----- GEMM4: sp[16][512] = soft @ Wi1shift^T + bi1 -----
  {
    f32x4 a4[8];
#pragma unroll
    for (int nt = 0; nt < 8; ++nt) a4[nt] = (f32x4){0.f, 0.f, 0.f, 0.f};
#pragma unroll
    for (int ks = 0; ks < 2; ++ks) {
      bf16x8 af = *(const bf16x8*)((char*)sb2 + ((l15 * 128 + ks * 64 + lg * 16) ^ ((l15 & 7) << 4)));
#pragma unroll
      for (int nt = 0; nt < 8; ++nt) {
        int c = w * 128 + nt * 16 + l15;
        bf16x8 bfr = *(const bf16x8*)(Wi1sb + (size_t)c * 64 + ks * 32 + lg * 8);
        a4[nt] = __builtin_amdgcn_mfma_f32_16x16x32_bf16(af, bfr, a4[nt], 0, 0, 0);
      }
    }
#pragma unroll
    for (int nt = 0; nt < 8; ++nt) {
      int c = w * 128 + nt * 16 + l15;
      float bb = bi1s[c];
#pragma unroll
      for (int r = 0; r < 4; ++r)
        sp[(size_t)(b0 + 4 * lg + r) * 512 + c] = a4[nt][r] + bb;
    }
  }
}

// ---------------- big9: in-reg fusion + bf16 single-stage partial reduction ----
// BM=64 (1 batch row), BN=512, 8 waves. h1[64][512] LDS (&15 swizzle), bf16 posT.
// GEMM1 = mfma(Wi2frag, h1frag), depth-4 B prefetch, setprio around MFMA.
// h2 in regs -> pack (verified R8) -> GEMM2 in-reg, all 8 waves K-split.
// Reduction: each wave stores its 64x64 bf16 partial to its own 8KB region
// (scalar b16 stores, j ^= 8*(p&7): 2-way banks = free). ONE barrier. Softmax
// sums 8 regions via bf16x8 b128 reads (same XOR involution), max-free.
__global__ __launch_bounds__(512, 4) void big9_kernel(
    const float* __restrict__ a_bits, const float* __restrict__ sp,
    const ushort_t* __restrict__ posTb,
    const ushort_t* __restrict__ Wi2f32, const ushort_t* __restrict__ Wi3g,
    const float* __restrict__ bi2, const float* __restrict__ bi3,
    float* __restrict__ out) {
  __shared__ __align__(16) ushort_t h1s[64 * 512];   // 64KB; reused as 8x8KB bf16 partials
  __shared__ float bi2s[512];
  __shared__ float ab[64];
  __shared__ float bi3s[64];

  int b = blockIdx.x, t = threadIdx.x;
  int w = t >> 6, l = t & 63;
  int l31 = l & 31, hi = l >> 5;

  bi2s[t] = bi2[t];
  if (t < 64) { ab[t] = a_bits[b * 64 + t]; bi3s[t] = bi3[t]; }

  // ---- phase 0: h1[64][512] = relu(sp[b] + pos) -> LDS bf16, swizzled, ONCE ----
  {
    const float* sprow = sp + (size_t)b * 512 + l * 8;
    float4 s0 = *(const float4*)(sprow);
    float4 s1 = *(const float4*)(sprow + 4);
#pragma unroll
    for (int g = 0; g < 8; ++g) {
      int p = g * 8 + w;                    // wave w covers rows {w, 8+w, ..., 56+w}
      bf16x8 pr = *(const bf16x8*)(posTb + (size_t)p * 512 + l * 8);
      float v0 = fmaxf(s0.x + bf2f(pr[0]), 0.f), v1 = fmaxf(s0.y + bf2f(pr[1]), 0.f);
      float v2 = fmaxf(s0.z + bf2f(pr[2]), 0.f), v3 = fmaxf(s0.w + bf2f(pr[3]), 0.f);
      float v4 = fmaxf(s1.x + bf2f(pr[4]), 0.f), v5 = fmaxf(s1.y + bf2f(pr[5]), 0.f);
      float v6 = fmaxf(s1.z + bf2f(pr[6]), 0.f), v7 = fmaxf(s1.w + bf2f(pr[7]), 0.f);
      uint4 pk;
      pk.x = pack2bf(v0, v1); pk.y = pack2bf(v2, v3);
      pk.z = pack2bf(v4, v5); pk.w = pack2bf(v6, v7);
      *(uint4*)((char*)h1s + ((p * 1024 + l * 16) ^ ((p & 15) << 4))) = pk;
    }
  }
  __syncthreads();

  // ---- GEMM1: mfma(Wi2, h1) ; 32x32x16, depth-4 B prefetch, barrier-free ----
  f32x16 acc[2][2];   // acc[mc][np]: reg<->c (c-tile mc), lane<->p (p-tile np)
#pragma unroll
  for (int mc = 0; mc < 2; ++mc)
#pragma unroll
    for (int np = 0; np < 2; ++np)
#pragma unroll
      for (int r = 0; r < 16; ++r) acc[mc][np][r] = 0.f;

  {
    const bf16x8* bbase = (const bf16x8*)Wi2f32 + ((size_t)(2 * w) * 64 + l);
    bf16x8 wf[4][2];
#pragma unroll
    for (int d = 0; d < 4; ++d) {
      wf[d][0] = bbase[(size_t)d * 1024];
      wf[d][1] = bbase[(size_t)d * 1024 + 64];
    }
    for (int kb = 0; kb < 8; ++kb) {
#pragma unroll
      for (int d = 0; d < 4; ++d) {
        int ks = kb * 4 + d;
        bf16x8 w0 = wf[d][0], w1 = wf[d][1];
        if (kb < 7) {
          wf[d][0] = bbase[(size_t)(ks + 4) * 1024];
          wf[d][1] = bbase[(size_t)(ks + 4) * 1024 + 64];
        }
        int row0 = l31, row1 = 32 + l31;
        bf16x8 h0 = *(const bf16x8*)((char*)h1s + ((row0 * 1024 + ks * 32 + hi * 16) ^ ((row0 & 15) << 4)));
        bf16x8 h1v = *(const bf16x8*)((char*)h1s + ((row1 * 1024 + ks * 32 + hi * 16) ^ ((row1 & 15) << 4)));
        __builtin_amdgcn_s_setprio(1);
        acc[0][0] = __builtin_amdgcn_mfma_f32_32x32x16_bf16(w0, h0, acc[0][0], 0, 0, 0);
        acc[0][1] = __builtin_amdgcn_mfma_f32_32x32x16_bf16(w0, h1v, acc[0][1], 0, 0, 0);
        acc[1][0] = __builtin_amdgcn_mfma_f32_32x32x16_bf16(w1, h0, acc[1][0], 0, 0, 0);
        acc[1][1] = __builtin_amdgcn_mfma_f32_32x32x16_bf16(w1, h1v, acc[1][1], 0, 0, 0);
        __builtin_amdgcn_s_setprio(0);
      }
    }
  }

  // ---- h2 = relu(acc + bi2), pack to bf16 A-frags in regs (layout verified R8) ----
  bf16x8 pkf[2][2][2];   // [np][mc][h]
#pragma unroll
  for (int mc = 0; mc < 2; ++mc) {
    float bia[16];
#pragma unroll
    for (int rq = 0; rq < 4; ++rq) {
      int c0 = w * 64 + mc * 32 + 8 * rq + 4 * hi;
      float4 bi4 = *(const float4*)(bi2s + c0);
      bia[4 * rq + 0] = bi4.x; bia[4 * rq + 1] = bi4.y;
      bia[4 * rq + 2] = bi4.z; bia[4 * rq + 3] = bi4.w;
    }
#pragma unroll
    for (int np = 0; np < 2; ++np) {
      float hv[16];
#pragma unroll
      for (int r = 0; r < 16; ++r) hv[r] = fmaxf(acc[mc][np][r] + bia[r], 0.f);
#pragma unroll
      for (int h = 0; h < 2; ++h) {
        unsigned d0 = pack2bf(hv[8 * h + 0], hv[8 * h + 1]);
        unsigned d1 = pack2bf(hv[8 * h + 2], hv[8 * h + 3]);
        unsigned d2 = pack2bf(hv[8 * h + 4], hv[8 * h + 5]);
        unsigned d3 = pack2bf(hv[8 * h + 6], hv[8 * h + 7]);
        union { unsigned u[4]; bf16x8 v; } cv;
        cv.u[0] = d0; cv.u[1] = d1; cv.u[2] = d2; cv.u[3] = d3;
        pkf[np][mc][h] = cv.v;
      }
    }
  }
  __syncthreads();   // all waves done reading h1s -> safe to reuse as partials

  // ---- GEMM2: partial logits over this wave's 64-c chunk, fully in-reg ----
  f32x16 l00, l01, l10, l11;
#pragma unroll
  for (int r = 0; r < 16; ++r) { l00[r] = 0.f; l01[r] = 0.f; l10[r] = 0.f; l11[r] = 0.f; }
  {
    const bf16x8* gbase = (const bf16x8*)Wi3g + ((size_t)w * 8 * 64 + l);
#pragma unroll
    for (int mc = 0; mc < 2; ++mc) {
#pragma unroll
      for (int h = 0; h < 2; ++h) {
        bf16x8 g0 = gbase[((mc * 2 + h) * 2 + 0) * 64];
        bf16x8 g1 = gbase[((mc * 2 + h) * 2 + 1) * 64];
        __builtin_amdgcn_s_setprio(1);
        l00 = __builtin_amdgcn_mfma_f32_32x32x16_bf16(pkf[0][mc][h], g0, l00, 0, 0, 0);
        l01 = __builtin_amdgcn_mfma_f32_32x32x16_bf16(pkf[0][mc][h], g1, l01, 0, 0, 0);
        l10 = __builtin_amdgcn_mfma_f32_32x32x16_bf16(pkf[1][mc][h], g0, l10, 0, 0, 0);
        l11 = __builtin_amdgcn_mfma_f32_32x32x16_bf16(pkf[1][mc][h], g1, l11, 0, 0, 0);
        __builtin_amdgcn_s_setprio(0);
      }
    }
  }

  // ---- store bf16 partial [w][p][j], j-octet XOR by (p&7): 2-way banks ----
  // D: lane<->j (jt*32+l31), reg<->p (np*32 + (r&3)+8*(r>>2)+4*hi)
  {
    ushort_t* Pr = h1s + (size_t)w * 4096;   // 8KB region per wave
#pragma unroll
    for (int r = 0; r < 16; ++r) {
      int p0 = (r & 3) + 8 * (r >> 2) + 4 * hi;
      int p1 = p0 + 32;
      Pr[p0 * 64 + ((l31)      ^ (8 * (p0 & 7)))] = f2bf(l00[r]);
      Pr[p0 * 64 + ((32 + l31) ^ (8 * (p0 & 7)))] = f2bf(l01[r]);
      Pr[p1 * 64 + ((l31)      ^ (8 * (p1 & 7)))] = f2bf(l10[r]);
      Pr[p1 * 64 + ((32 + l31) ^ (8 * (p1 & 7)))] = f2bf(l11[r]);
    }
  }
  __syncthreads();

  // ---- max-free softmax + gather: thread (p = t>>3, jo = t&7) sums 8 regions ----
  {
    int p = t >> 3, jo = t & 7;
    int off = p * 64 + ((jo ^ (p & 7)) * 8);
    float sum[8] = {0.f, 0.f, 0.f, 0.f, 0.f, 0.f, 0.f, 0.f};
#pragma unroll
    for (int wr = 0; wr < 8; ++wr) {
      bf16x8 v = *(const bf16x8*)(h1s + wr * 4096 + off);
#pragma unroll
      for (int m = 0; m < 8; ++m) sum[m] += bf2f(v[m]);
    }
    float s = 0.f, g = 0.f;
#pragma unroll
    for (int m = 0; m < 8; ++m) {
      int c = jo * 8 + m;
      float e = __expf(sum[m] + bi3s[c]);
      s += e; g += e * ab[c];
    }
#pragma unroll
    for (int mm = 4; mm >= 1; mm >>= 1) { s += __shfl_xor(s, mm); g += __shfl_xor(g, mm); }
    if (jo == 0) out[b * 64 + p] = g / s;
  }
}

extern "C" void kernel_launch(void* const* d_in, const int* in_sizes, int n_in,
                              void* d_out, int out_size, void* d_ws, size_t ws_size,
                              hipStream_t stream) {
  const float* a_bits     = (const float*)d_in[0];
  const float* shift_bits = (const float*)d_in[1];
  const float* W1  = (const float*)d_in[2];
  const float* b1  = (const float*)d_in[3];
  const float* g1  = (const float*)d_in[4];
  const float* be1 = (const float*)d_in[5];
  const float* W2  = (const float*)d_in[6];
  const float* b2  = (const float*)d_in[7];
  const float* g2  = (const float*)d_in[8];
  const float* be2 = (const float*)d_in[9];
  const float* W3  = (const float*)d_in[10];
  const float* b3  = (const float*)d_in[11];
  const float* Wi1 = (const float*)d_in[12];
  const float* bi1 = (const float*)d_in[13];
  const float* Wi2 = (const float*)d_in[14];
  const float* bi2 = (const float*)d_in[15];
  const float* Wi3 = (const float*)d_in[16];
  const float* bi3 = (const float*)d_in[17];
  float* out = (float*)d_out;

  // ws layout: sp fp32 [B][512] (8MB) | W2f (512KB) | W1b (64KB) | W3b (64KB)
  //            | Wi1sb (64KB) | Wi1posTb bf16 (64KB) | Wi2f32 (512KB) | Wi3g (64KB)
  float* sp = (float*)d_ws;
  ushort_t* W2f = (ushort_t*)((char*)d_ws + (size_t)B_N * HID * 4);
  ushort_t* W1b = W2f + 512 * 512;
  ushort_t* W3b = W1b + 512 * 64;
  ushort_t* Wi1sb = W3b + 64 * 512;
  ushort_t* Wi1posTb = Wi1sb + 512 * 64;
  ushort_t* Wi2f32 = Wi1posTb + 64 * 512;
  ushort_t* Wi3g = Wi2f32 + 512 * 512;

  prep_kernel<<<1024, 256, 0, stream>>>(Wi2, Wi3, Wi1, W1, W2, W3,
                                        Wi1posTb, W1b, W2f, W3b, Wi1sb, Wi2f32, Wi3g);
  shift2_kernel<<<B_N / BT, 256, 0, stream>>>(shift_bits, W1b, b1, g1, be1,
                                              W2f, b2, g2, be2, W3b, b3, Wi1sb, bi1, sp);
  big9_kernel<<<B_N, 512, 0, stream>>>(a_bits, sp, Wi1posTb, Wi2f32, Wi3g, bi2, bi3, out);
}

// Round 11
// 202.225 us; speedup vs baseline: 4.0484x; 1.0001x over previous
//
#include <hip/hip_runtime.h>
#include <hip/hip_bf16.h>
#include <math.h>

// Problem constants
#define B_N 4096
#define BITSN 64
#define HID 512
#define EPSV 1e-5f
#define BT 16   // batch rows per shift2 block

typedef unsigned short ushort_t;
typedef __attribute__((ext_vector_type(8))) short bf16x8;
typedef __attribute__((ext_vector_type(4))) float f32x4;
typedef __attribute__((ext_vector_type(16))) float f32x16;

__device__ __forceinline__ ushort_t f2bf(float f) {
  unsigned u = __float_as_uint(f);
  u += 0x7FFF + ((u >> 16) & 1);   // round-to-nearest-even
  return (ushort_t)(u >> 16);
}

__device__ __forceinline__ unsigned pack2bf(float lo, float hi) {
  union { __hip_bfloat162 h; unsigned u; } cv;
  cv.h = __float22bfloat162_rn(make_float2(lo, hi));  // v_cvt_pk_bf16_f32
  return cv.u;
}

__device__ __forceinline__ float bf2f(short v) {
  return __uint_as_float(((unsigned)(unsigned short)v) << 16);
}

// ---------------- prep: bf16 copies, transposes, FRAGMENT-ORDER weights ----
// Wi2f32: 32x32x16 frag order (big GEMM1 B). Frag (ks 0..31, ct 0..15) lane l:
//   Wi2[ct*32 + (l&31)][ks*16 + (l>>5)*8 + j].
// W2f: 16x16x32 frag order (shift2 GEMM2 B, verified R5/R10).
// Wi3f: 16x16x32 frag order (big GEMM2 B, verified R5 in big4/big5):
//   idx=((ks2*4+nt)*64+lane)*8+j -> Wi3[nt*16+(lane&15)][ks2*32+(lane>>4)*8+j].
// Wi1posTb: bf16 pos_part transpose [64][512].
__global__ __launch_bounds__(256) void prep_kernel(
    const float* __restrict__ Wi2, const float* __restrict__ Wi3,
    const float* __restrict__ Wi1, const float* __restrict__ W1,
    const float* __restrict__ W2, const float* __restrict__ W3,
    ushort_t* __restrict__ Wi1posTb, ushort_t* __restrict__ W1b,
    ushort_t* __restrict__ W2f, ushort_t* __restrict__ W3b,
    ushort_t* __restrict__ Wi1sb, ushort_t* __restrict__ Wi2f32,
    ushort_t* __restrict__ Wi3f) {
  int idx = blockIdx.x * 256 + threadIdx.x;
  if (idx < 512 * 512) {
    // W2f (16x16x32 frag order) for shift2 GEMM2
    {
      int j = idx & 7, lane = (idx >> 3) & 63;
      int ct = (idx >> 9) & 31, ks = idx >> 14;
      int c = ct * 16 + (lane & 15);
      int k = ks * 32 + (lane >> 4) * 8 + j;
      W2f[idx] = f2bf(W2[c * 512 + k]);
    }
    // Wi2f32 (32x32x16 frag order) for big GEMM1
    {
      int j = idx & 7, lane = (idx >> 3) & 63;
      int ct = (idx >> 9) & 15, ks = idx >> 13;
      int c = ct * 32 + (lane & 31);
      int k = ks * 16 + (lane >> 5) * 8 + j;
      Wi2f32[idx] = f2bf(Wi2[c * 512 + k]);
    }
  }
  if (idx < 64 * 512) {
    W3b[idx] = f2bf(W3[idx]);
    int p = idx >> 9, i = idx & 511;
    Wi1posTb[idx] = f2bf(Wi1[i * 128 + p]);   // pos_part[p][i] = Wi1[i][p], bf16
    // Wi3f frag-order (16x16x32), verified R5
    int j = idx & 7, lane = (idx >> 3) & 63;
    int nt = (idx >> 9) & 3, ks2 = idx >> 11;
    int jr = nt * 16 + (lane & 15);
    int k = ks2 * 32 + (lane >> 4) * 8 + j;
    Wi3f[idx] = f2bf(Wi3[jr * 512 + k]);
  }
  if (idx < 512 * 64) {
    W1b[idx] = f2bf(W1[idx]);                       // [512][64]
    int j = idx >> 6, k = idx & 63;
    Wi1sb[idx] = f2bf(Wi1[j * 128 + 64 + k]);       // shift cols of Wi1: [512][64]
  }
}

// ---------------- shift decoder, MFMA-batched: 16 rows/block ----------------
__global__ __launch_bounds__(256) void shift2_kernel(
    const float* __restrict__ shift_bits,
    const ushort_t* __restrict__ W1b, const float* __restrict__ b1,
    const float* __restrict__ g1, const float* __restrict__ be1,
    const ushort_t* __restrict__ W2f, const float* __restrict__ b2,
    const float* __restrict__ g2, const float* __restrict__ be2,
    const ushort_t* __restrict__ W3b, const float* __restrict__ b3,
    const ushort_t* __restrict__ Wi1sb, const float* __restrict__ bi1,
    float* __restrict__ sp) {
  __shared__ __align__(16) ushort_t hA[BT * 512];     // 16KB: h1 (post LN1+relu)
  __shared__ __align__(16) char reg2[32 * 1024];      // phase union
  __shared__ float b1s[512], g1s[512], be1s[512];
  __shared__ float b2s[512], g2s[512], be2s[512], bi1s[512];
  __shared__ float red[4][BT][2];
  __shared__ float b3s[64];

  ushort_t* sbt = (ushort_t*)reg2;                    // phase 1: shift_bits tile [16][64]
  ushort_t* h2  = (ushort_t*)reg2;                    // phase 3: h2 [16][512]
  float (*lg32)[68] = (float(*)[68])(reg2 + 16 * 1024);
  ushort_t* sb2 = (ushort_t*)(reg2 + 16 * 1024 + 16 * 68 * 4);  // soft [16][64]

  int b0 = blockIdx.x * BT;
  int t = threadIdx.x, w = t >> 6, l = t & 63, lg = l >> 4, l15 = l & 15;

  b1s[t] = b1[t];  b1s[t + 256] = b1[t + 256];
  g1s[t] = g1[t];  g1s[t + 256] = g1[t + 256];
  be1s[t] = be1[t]; be1s[t + 256] = be1[t + 256];
  b2s[t] = b2[t];  b2s[t + 256] = b2[t + 256];
  g2s[t] = g2[t];  g2s[t + 256] = g2[t + 256];
  be2s[t] = be2[t]; be2s[t + 256] = be2[t + 256];
  bi1s[t] = bi1[t]; bi1s[t + 256] = bi1[t + 256];
  if (t < 64) b3s[t] = b3[t];
  if (t < 128) {   // stage shift_bits tile -> bf16 swizzled
    int row = t >> 3, g = t & 7;
    const float* src = shift_bits + (size_t)(b0 + row) * 64 + g * 8;
    uint4 pk;
    pk.x = (unsigned)f2bf(src[0]) | ((unsigned)f2bf(src[1]) << 16);
    pk.y = (unsigned)f2bf(src[2]) | ((unsigned)f2bf(src[3]) << 16);
    pk.z = (unsigned)f2bf(src[4]) | ((unsigned)f2bf(src[5]) << 16);
    pk.w = (unsigned)f2bf(src[6]) | ((unsigned)f2bf(src[7]) << 16);
    *(uint4*)((char*)sbt + ((row * 128 + g * 16) ^ ((row & 7) << 4))) = pk;
  }
  __syncthreads();

  // ----- GEMM1: x1[16][512] = sbt @ W1^T ; wave w owns cols [w*128, w*128+128) -----
  f32x4 acc[8];
#pragma unroll
  for (int nt = 0; nt < 8; ++nt) acc[nt] = (f32x4){0.f, 0.f, 0.f, 0.f};
#pragma unroll
  for (int ks = 0; ks < 2; ++ks) {
    bf16x8 af = *(const bf16x8*)((char*)sbt + ((l15 * 128 + ks * 64 + lg * 16) ^ ((l15 & 7) << 4)));
#pragma unroll
    for (int nt = 0; nt < 8; ++nt) {
      int c = w * 128 + nt * 16 + l15;
      bf16x8 bfr = *(const bf16x8*)(W1b + (size_t)c * 64 + ks * 32 + lg * 8);
      acc[nt] = __builtin_amdgcn_mfma_f32_16x16x32_bf16(af, bfr, acc[nt], 0, 0, 0);
    }
  }
  // ----- LN1 + relu -> hA -----
  {
    float s[4] = {0.f, 0.f, 0.f, 0.f}, q[4] = {0.f, 0.f, 0.f, 0.f};
#pragma unroll
    for (int nt = 0; nt < 8; ++nt) {
      int c = w * 128 + nt * 16 + l15;
      float bb = b1s[c];
#pragma unroll
      for (int r = 0; r < 4; ++r) {
        float x = acc[nt][r] + bb;
        acc[nt][r] = x;
        s[r] += x; q[r] += x * x;
      }
    }
#pragma unroll
    for (int m = 8; m >= 1; m >>= 1)
#pragma unroll
      for (int r = 0; r < 4; ++r) { s[r] += __shfl_xor(s[r], m); q[r] += __shfl_xor(q[r], m); }
    if (l15 == 0)
#pragma unroll
      for (int r = 0; r < 4; ++r) { red[w][4 * lg + r][0] = s[r]; red[w][4 * lg + r][1] = q[r]; }
    __syncthreads();
    float mean[4], rs[4];
#pragma unroll
    for (int r = 0; r < 4; ++r) {
      int p = 4 * lg + r;
      float S = red[0][p][0] + red[1][p][0] + red[2][p][0] + red[3][p][0];
      float Q = red[0][p][1] + red[1][p][1] + red[2][p][1] + red[3][p][1];
      mean[r] = S * (1.0f / 512.0f);
      float var = Q * (1.0f / 512.0f) - mean[r] * mean[r];
      rs[r] = rsqrtf(var + EPSV);
    }
#pragma unroll
    for (int nt = 0; nt < 8; ++nt) {
      int c = w * 128 + nt * 16 + l15;
      float gg = g1s[c], bb = be1s[c];
#pragma unroll
      for (int r = 0; r < 4; ++r) {
        int p = 4 * lg + r;
        float v = (acc[nt][r] - mean[r]) * rs[r] * gg + bb;
        v = v > 0.f ? v : 0.f;
        *(ushort_t*)((char*)hA + ((p * 1024 + c * 2) ^ ((p & 7) << 4))) = f2bf(v);
      }
    }
  }
  __syncthreads();

  // ----- GEMM2: x2[16][512] = hA @ W2^T, frag-order W2f, barrier-free -----
#pragma unroll
  for (int nt = 0; nt < 8; ++nt) acc[nt] = (f32x4){0.f, 0.f, 0.f, 0.f};
  {
    const bf16x8* w2base = (const bf16x8*)W2f + ((size_t)(w * 8) * 64 + l);
#pragma unroll 2
    for (int step = 0; step < 16; ++step) {
      bf16x8 af = *(const bf16x8*)((char*)hA + ((l15 * 1024 + step * 64 + lg * 16) ^ ((l15 & 7) << 4)));
#pragma unroll
      for (int nt = 0; nt < 8; ++nt) {
        bf16x8 bfr = w2base[((size_t)step * 32 + nt) * 64];
        acc[nt] = __builtin_amdgcn_mfma_f32_16x16x32_bf16(af, bfr, acc[nt], 0, 0, 0);
      }
    }
  }
  __syncthreads();   // hA reads done; h2 region (reg2) free for overwrite
  // ----- LN2 + relu -> h2 -----
  {
    float s[4] = {0.f, 0.f, 0.f, 0.f}, q[4] = {0.f, 0.f, 0.f, 0.f};
#pragma unroll
    for (int nt = 0; nt < 8; ++nt) {
      int c = w * 128 + nt * 16 + l15;
      float bb = b2s[c];
#pragma unroll
      for (int r = 0; r < 4; ++r) {
        float x = acc[nt][r] + bb;
        acc[nt][r] = x;
        s[r] += x; q[r] += x * x;
      }
    }
#pragma unroll
    for (int m = 8; m >= 1; m >>= 1)
#pragma unroll
      for (int r = 0; r < 4; ++r) { s[r] += __shfl_xor(s[r], m); q[r] += __shfl_xor(q[r], m); }
    if (l15 == 0)
#pragma unroll
      for (int r = 0; r < 4; ++r) { red[w][4 * lg + r][0] = s[r]; red[w][4 * lg + r][1] = q[r]; }
    __syncthreads();
    float mean[4], rs[4];
#pragma unroll
    for (int r = 0; r < 4; ++r) {
      int p = 4 * lg + r;
      float S = red[0][p][0] + red[1][p][0] + red[2][p][0] + red[3][p][0];
      float Q = red[0][p][1] + red[1][p][1] + red[2][p][1] + red[3][p][1];
      mean[r] = S * (1.0f / 512.0f);
      float var = Q * (1.0f / 512.0f) - mean[r] * mean[r];
      rs[r] = rsqrtf(var + EPSV);
    }
#pragma unroll
    for (int nt = 0; nt < 8; ++nt) {
      int c = w * 128 + nt * 16 + l15;
      float gg = g2s[c], bb = be2s[c];
#pragma unroll
      for (int r = 0; r < 4; ++r) {
        int p = 4 * lg + r;
        float v = (acc[nt][r] - mean[r]) * rs[r] * gg + bb;
        v = v > 0.f ? v : 0.f;
        *(ushort_t*)((char*)h2 + ((p * 1024 + c * 2) ^ ((p & 7) << 4))) = f2bf(v);
      }
    }
  }
  __syncthreads();

  // ----- GEMM3: logits[16][64] = h2 @ W3^T ; wave w owns cols [16w,16w+16) -----
  {
    f32x4 a3 = (f32x4){0.f, 0.f, 0.f, 0.f};
#pragma unroll
    for (int ks = 0; ks < 16; ++ks) {
      bf16x8 af = *(const bf16x8*)((char*)h2 + ((l15 * 1024 + ks * 64 + lg * 16) ^ ((l15 & 7) << 4)));
      bf16x8 bfr = *(const bf16x8*)(W3b + (size_t)(w * 16 + l15) * 512 + ks * 32 + lg * 8);
      a3 = __builtin_amdgcn_mfma_f32_16x16x32_bf16(af, bfr, a3, 0, 0, 0);
    }
    int c = w * 16 + l15;
    float bb = b3s[c];
#pragma unroll
    for (int r = 0; r < 4; ++r) lg32[4 * lg + r][c] = a3[r] + bb;
  }
  __syncthreads();

  // ----- softmax over 64 logits -> sb2 (bf16, swizzled) -----
  {
    int r = t >> 4, j = t & 15;
    float v[4];
    float m = -1e30f;
#pragma unroll
    for (int mq = 0; mq < 4; ++mq) { v[mq] = lg32[r][mq * 16 + j]; m = fmaxf(m, v[mq]); }
#pragma unroll
    for (int mk = 8; mk >= 1; mk >>= 1) m = fmaxf(m, __shfl_xor(m, mk));
    float ssum = 0.f;
#pragma unroll
    for (int mq = 0; mq < 4; ++mq) { v[mq] = expf(v[mq] - m); ssum += v[mq]; }
#pragma unroll
    for (int mk = 8; mk >= 1; mk >>= 1) ssum += __shfl_xor(ssum, mk);
    float inv = 1.f / ssum;
#pragma unroll
    for (int mq = 0; mq < 4; ++mq) {
      int c = mq * 16 + j;
      *(ushort_t*)((char*)sb2 + ((r * 128 + c * 2) ^ ((r & 7) << 4))) = f2bf(v[mq] * inv);
    }
  }
  __syncthreads();

  // ----- GEMM4: sp[16][512] = soft @ Wi1shift^T + bi1 -----
  {
    f32x4 a4[8];
#pragma unroll
    for (int nt = 0; nt < 8; ++nt) a4[nt] = (f32x4){0.f, 0.f, 0.f, 0.f};
#pragma unroll
    for (int ks = 0; ks < 2; ++ks) {
      bf16x8 af = *(const bf16x8*)((char*)sb2 + ((l15 * 128 + ks * 64 + lg * 16) ^ ((l15 & 7) << 4)));
#pragma unroll
      for (int nt = 0; nt < 8; ++nt) {
        int c = w * 128 + nt * 16 + l15;
        bf16x8 bfr = *(const bf16x8*)(Wi1sb + (size_t)c * 64 + ks * 32 + lg * 8);
        a4[nt] = __builtin_amdgcn_mfma_f32_16x16x32_bf16(af, bfr, a4[nt], 0, 0, 0);
      }
    }
#pragma unroll
    for (int nt = 0; nt < 8; ++nt) {
      int c = w * 128 + nt * 16 + l15;
      float bb = bi1s[c];
#pragma unroll
      for (int r = 0; r < 4; ++r)
        sp[(size_t)(b0 + 4 * lg + r) * 512 + c] = a4[nt][r] + bb;
    }
  }
}

// ---------------- big10: GEMM1(in-reg B) -> h2 LDS -> 8-wave output-split GEMM2 ----
// BM=64 (1 batch row), BN=512, 8 waves. h1[64][512] LDS (&15 swizzle), bf16 posT.
// GEMM1 = mfma(Wi2frag, h1frag): reg<->c, lane<->p; depth-4 B prefetch; setprio.
// h2 = relu(acc+bi2) -> LDS via packed uint2 writes (big6-verified layout).
// GEMM2: NO K-split, NO reduction: wave w = (p-tile w>>1 of 16 rows, j-half w&1);
// full K=512 per wave with 16x16x32 mfma against Wi3f (R5-verified frag order).
// Logits written once to f32 [64][pitch 68] (aliases h1s AFTER a barrier).
__global__ __launch_bounds__(512, 4) void big10_kernel(
    const float* __restrict__ a_bits, const float* __restrict__ sp,
    const ushort_t* __restrict__ posTb,
    const ushort_t* __restrict__ Wi2f32, const ushort_t* __restrict__ Wi3f,
    const float* __restrict__ bi2, const float* __restrict__ bi3,
    float* __restrict__ out) {
  __shared__ __align__(16) ushort_t h1s[64 * 512];   // 64KB; h1 -> h2 -> logits
  __shared__ float bi2s[512];
  __shared__ float ab[64];
  __shared__ float bi3s[64];

  int b = blockIdx.x, t = threadIdx.x;
  int w = t >> 6, l = t & 63;
  int l31 = l & 31, hi = l >> 5;
  int lg = l >> 4, l15 = l & 15;

  bi2s[t] = bi2[t];
  if (t < 64) { ab[t] = a_bits[b * 64 + t]; bi3s[t] = bi3[t]; }

  // ---- phase 0: h1[64][512] = relu(sp[b] + pos) -> LDS bf16, swizzled, ONCE ----
  {
    const float* sprow = sp + (size_t)b * 512 + l * 8;
    float4 s0 = *(const float4*)(sprow);
    float4 s1 = *(const float4*)(sprow + 4);
#pragma unroll
    for (int g = 0; g < 8; ++g) {
      int p = g * 8 + w;                    // wave w covers rows {w, 8+w, ..., 56+w}
      bf16x8 pr = *(const bf16x8*)(posTb + (size_t)p * 512 + l * 8);
      float v0 = fmaxf(s0.x + bf2f(pr[0]), 0.f), v1 = fmaxf(s0.y + bf2f(pr[1]), 0.f);
      float v2 = fmaxf(s0.z + bf2f(pr[2]), 0.f), v3 = fmaxf(s0.w + bf2f(pr[3]), 0.f);
      float v4 = fmaxf(s1.x + bf2f(pr[4]), 0.f), v5 = fmaxf(s1.y + bf2f(pr[5]), 0.f);
      float v6 = fmaxf(s1.z + bf2f(pr[6]), 0.f), v7 = fmaxf(s1.w + bf2f(pr[7]), 0.f);
      uint4 pk;
      pk.x = pack2bf(v0, v1); pk.y = pack2bf(v2, v3);
      pk.z = pack2bf(v4, v5); pk.w = pack2bf(v6, v7);
      *(uint4*)((char*)h1s + ((p * 1024 + l * 16) ^ ((p & 15) << 4))) = pk;
    }
  }
  __syncthreads();

  // ---- GEMM1: mfma(Wi2, h1) ; 32x32x16, depth-4 B prefetch, barrier-free ----
  f32x16 acc[2][2];   // acc[mc][np]: reg<->c (c-tile mc), lane<->p (p-tile np)
#pragma unroll
  for (int mc = 0; mc < 2; ++mc)
#pragma unroll
    for (int np = 0; np < 2; ++np)
#pragma unroll
      for (int r = 0; r < 16; ++r) acc[mc][np][r] = 0.f;

  {
    const bf16x8* bbase = (const bf16x8*)Wi2f32 + ((size_t)(2 * w) * 64 + l);
    bf16x8 wf[4][2];
#pragma unroll
    for (int d = 0; d < 4; ++d) {
      wf[d][0] = bbase[(size_t)d * 1024];
      wf[d][1] = bbase[(size_t)d * 1024 + 64];
    }
    for (int kb = 0; kb < 8; ++kb) {
#pragma unroll
      for (int d = 0; d < 4; ++d) {
        int ks = kb * 4 + d;
        bf16x8 w0 = wf[d][0], w1 = wf[d][1];
        if (kb < 7) {
          wf[d][0] = bbase[(size_t)(ks + 4) * 1024];
          wf[d][1] = bbase[(size_t)(ks + 4) * 1024 + 64];
        }
        int row0 = l31, row1 = 32 + l31;
        bf16x8 h0 = *(const bf16x8*)((char*)h1s + ((row0 * 1024 + ks * 32 + hi * 16) ^ ((row0 & 15) << 4)));
        bf16x8 h1v = *(const bf16x8*)((char*)h1s + ((row1 * 1024 + ks * 32 + hi * 16) ^ ((row1 & 15) << 4)));
        __builtin_amdgcn_s_setprio(1);
        acc[0][0] = __builtin_amdgcn_mfma_f32_32x32x16_bf16(w0, h0, acc[0][0], 0, 0, 0);
        acc[0][1] = __builtin_amdgcn_mfma_f32_32x32x16_bf16(w0, h1v, acc[0][1], 0, 0, 0);
        acc[1][0] = __builtin_amdgcn_mfma_f32_32x32x16_bf16(w1, h0, acc[1][0], 0, 0, 0);
        acc[1][1] = __builtin_amdgcn_mfma_f32_32x32x16_bf16(w1, h1v, acc[1][1], 0, 0, 0);
        __builtin_amdgcn_s_setprio(0);
      }
    }
  }
  __syncthreads();   // all waves done reading h1 -> safe to overwrite with h2

  // ---- h2 = relu(acc + bi2) -> h1s region, packed uint2 writes (big6-verified) ----
  // p = np*32 + l31 ; c = w*64 + mc*32 + (r&3) + 8*(r>>2) + 4*hi
#pragma unroll
  for (int mc = 0; mc < 2; ++mc) {
#pragma unroll
    for (int np = 0; np < 2; ++np) {
      int p = np * 32 + l31;
#pragma unroll
      for (int rq = 0; rq < 4; ++rq) {
        int c0 = w * 64 + mc * 32 + 8 * rq + 4 * hi;
        float4 bi4 = *(const float4*)(bi2s + c0);
        float v0 = fmaxf(acc[mc][np][4 * rq + 0] + bi4.x, 0.f);
        float v1 = fmaxf(acc[mc][np][4 * rq + 1] + bi4.y, 0.f);
        float v2 = fmaxf(acc[mc][np][4 * rq + 2] + bi4.z, 0.f);
        float v3 = fmaxf(acc[mc][np][4 * rq + 3] + bi4.w, 0.f);
        uint2 pk;
        pk.x = pack2bf(v0, v1);
        pk.y = pack2bf(v2, v3);
        *(uint2*)((char*)h1s + ((p * 1024 + c0 * 2) ^ ((p & 15) << 4))) = pk;
      }
    }
  }
  __syncthreads();

  // ---- GEMM2 (all 8 waves, output-split, full K, NO reduction) ----
  // wave w: p-tile pw = w>>1 (16 rows), j-half jh = w&1 (2 j-tiles of 16)
  f32x4 lacc[2];
  lacc[0] = (f32x4){0.f, 0.f, 0.f, 0.f};
  lacc[1] = (f32x4){0.f, 0.f, 0.f, 0.f};
  {
    int pw = w >> 1, jh = w & 1;
    int p2 = 16 * pw + l15;
    const bf16x8* b3base = (const bf16x8*)Wi3f + l;
#pragma unroll 4
    for (int ks2 = 0; ks2 < 16; ++ks2) {
      bf16x8 a2 = *(const bf16x8*)((char*)h1s + ((p2 * 1024 + ks2 * 64 + lg * 16) ^ ((p2 & 15) << 4)));
      bf16x8 g0 = b3base[(ks2 * 4 + 2 * jh + 0) * 64];
      bf16x8 g1 = b3base[(ks2 * 4 + 2 * jh + 1) * 64];
      __builtin_amdgcn_s_setprio(1);
      lacc[0] = __builtin_amdgcn_mfma_f32_16x16x32_bf16(a2, g0, lacc[0], 0, 0, 0);
      lacc[1] = __builtin_amdgcn_mfma_f32_16x16x32_bf16(a2, g1, lacc[1], 0, 0, 0);
      __builtin_amdgcn_s_setprio(0);
    }
  }
  __syncthreads();   // all waves done reading h2 -> safe to overwrite with logits

  // ---- logits -> LDS f32 [64][pitch 68] (2-way banks), written ONCE ----
  {
    float* Lg = (float*)h1s;
    int pw = w >> 1, jh = w & 1;
#pragma unroll
    for (int q = 0; q < 2; ++q) {
      int j = (2 * jh + q) * 16 + l15;
#pragma unroll
      for (int r = 0; r < 4; ++r) {
        int p = pw * 16 + 4 * lg + r;
        Lg[p * 68 + j] = lacc[q][r];
      }
    }
  }
  __syncthreads();

  // ---- max-free softmax + gather (verified R8: logits tiny, exp safe) ----
  {
    const float* Lg = (const float*)h1s;
    int p = t >> 3, jo = t & 7;
    float s = 0.f, g = 0.f;
#pragma unroll
    for (int m = 0; m < 8; ++m) {
      int c = jo * 8 + m;
      float e = __expf(Lg[p * 68 + c] + bi3s[c]);
      s += e; g += e * ab[c];
    }
#pragma unroll
    for (int mm = 4; mm >= 1; mm >>= 1) { s += __shfl_xor(s, mm); g += __shfl_xor(g, mm); }
    if (jo == 0) out[b * 64 + p] = g / s;
  }
}

extern "C" void kernel_launch(void* const* d_in, const int* in_sizes, int n_in,
                              void* d_out, int out_size, void* d_ws, size_t ws_size,
                              hipStream_t stream) {
  const float* a_bits     = (const float*)d_in[0];
  const float* shift_bits = (const float*)d_in[1];
  const float* W1  = (const float*)d_in[2];
  const float* b1  = (const float*)d_in[3];
  const float* g1  = (const float*)d_in[4];
  const float* be1 = (const float*)d_in[5];
  const float* W2  = (const float*)d_in[6];
  const float* b2  = (const float*)d_in[7];
  const float* g2  = (const float*)d_in[8];
  const float* be2 = (const float*)d_in[9];
  const float* W3  = (const float*)d_in[10];
  const float* b3  = (const float*)d_in[11];
  const float* Wi1 = (const float*)d_in[12];
  const float* bi1 = (const float*)d_in[13];
  const float* Wi2 = (const float*)d_in[14];
  const float* bi2 = (const float*)d_in[15];
  const float* Wi3 = (const float*)d_in[16];
  const float* bi3 = (const float*)d_in[17];
  float* out = (float*)d_out;

  // ws layout: sp fp32 [B][512] (8MB) | W2f (512KB) | W1b (64KB) | W3b (64KB)
  //            | Wi1sb (64KB) | Wi1posTb bf16 (64KB) | Wi2f32 (512KB) | Wi3f (64KB)
  float* sp = (float*)d_ws;
  ushort_t* W2f = (ushort_t*)((char*)d_ws + (size_t)B_N * HID * 4);
  ushort_t* W1b = W2f + 512 * 512;
  ushort_t* W3b = W1b + 512 * 64;
  ushort_t* Wi1sb = W3b + 64 * 512;
  ushort_t* Wi1posTb = Wi1sb + 512 * 64;
  ushort_t* Wi2f32 = Wi1posTb + 64 * 512;
  ushort_t* Wi3f = Wi2f32 + 512 * 512;

  prep_kernel<<<1024, 256, 0, stream>>>(Wi2, Wi3, Wi1, W1, W2, W3,
                                        Wi1posTb, W1b, W2f, W3b, Wi1sb, Wi2f32, Wi3f);
  shift2_kernel<<<B_N / BT, 256, 0, stream>>>(shift_bits, W1b, b1, g1, be1,
                                              W2f, b2, g2, be2, W3b, b3, Wi1sb, bi1, sp);
  big10_kernel<<<B_N, 512, 0, stream>>>(a_bits, sp, Wi1posTb, Wi2f32, Wi3f, bi2, bi3, out);
}